// Round 16
// baseline (527.714 us; speedup 1.0000x reference)
//
#include <hip/hip_runtime.h>
#include <hip/hip_bf16.h>
#include <stdint.h>

#define BB 16
#define SEQ 1024
#define CHN 512
#define NH 8
#define DH 64

typedef short short8 __attribute__((ext_vector_type(8)));
typedef short short4v __attribute__((ext_vector_type(4)));
typedef float f32x4 __attribute__((ext_vector_type(4)));

typedef const __attribute__((address_space(1))) unsigned int* gptr_t;
typedef __attribute__((address_space(3))) unsigned int* lptr_t;

__device__ __forceinline__ void async16(const void* g, void* l) {
    __builtin_amdgcn_global_load_lds((gptr_t)g, (lptr_t)l, 16, 0, 0);
}

__device__ __forceinline__ unsigned short f2bf(float f) {
    unsigned int u = __float_as_uint(f);
    u += 0x7FFF + ((u >> 16) & 1);
    return (unsigned short)(u >> 16);
}

// ---------------- convert f32 -> bf16 (3 tensors, one launch) ----------------
// At HBM roofline (144 MB @ ~6 TB/s ~= 24 us) — do not fuse into the GEMM
// (round-10 regression: f32 A re-read 4x + sync reg-staging -> qkv 38->98us).
__global__ __launch_bounds__(256) void k_cvt3(const float* __restrict__ a, const float* __restrict__ b,
                                              const float* __restrict__ c,
                                              unsigned short* __restrict__ oa, unsigned short* __restrict__ ob,
                                              unsigned short* __restrict__ oc, int n4) {
    int i = blockIdx.x * 256 + threadIdx.x;
    if (i >= n4) return;
    const float* in = (blockIdx.y == 0) ? a : (blockIdx.y == 1) ? b : c;
    unsigned short* out = (blockIdx.y == 0) ? oa : (blockIdx.y == 1) ? ob : oc;
    float4 v = ((const float4*)in)[i];
    ushort4 o;
    o.x = f2bf(v.x); o.y = f2bf(v.y); o.z = f2bf(v.z); o.w = f2bf(v.w);
    ((ushort4*)out)[i] = o;
}

// ------- convert + transpose weights: W[k][n] -> Wt[n][k] bf16 (4 weights, one launch) -------
__global__ __launch_bounds__(256) void k_cvtw4(const float* __restrict__ W0, const float* __restrict__ W1,
                                               const float* __restrict__ W2, const float* __restrict__ W3,
                                               unsigned short* __restrict__ T0, unsigned short* __restrict__ T1,
                                               unsigned short* __restrict__ T2, unsigned short* __restrict__ T3) {
    __shared__ float t[32][33];
    int z = blockIdx.z;
    const float* W = (z == 0) ? W0 : (z == 1) ? W1 : (z == 2) ? W2 : W3;
    unsigned short* Wt = (z == 0) ? T0 : (z == 1) ? T1 : (z == 2) ? T2 : T3;
    int n0 = blockIdx.x * 32, k0 = blockIdx.y * 32;
    int tx = threadIdx.x & 31, ty = threadIdx.x >> 5;
    for (int r = ty; r < 32; r += 8) t[r][tx] = W[(k0 + r) * CHN + n0 + tx];
    __syncthreads();
    for (int r = ty; r < 32; r += 8) Wt[(n0 + r) * CHN + k0 + tx] = f2bf(t[tx][r]);
}

// ---------- shared GEMM core, BK=64: A[M,K] x Bt[N,K] (both bf16 row-major) ----------
__device__ __forceinline__ void gemm_tile64(const unsigned short* __restrict__ A,
                                            const unsigned short* __restrict__ Bt,
                                            int Kdim, int m0, int n0,
                                            f32x4 acc[4][4],
                                            unsigned short* As, unsigned short* Bs) {
    const int tid = threadIdx.x;
    const int lane = tid & 63, wid = tid >> 6;
    const int g = lane >> 4, l16 = lane & 15;
    const int wm = wid >> 1, wn = wid & 1;
    for (int i = 0; i < 4; i++)
        for (int j = 0; j < 4; j++) acc[i][j] = (f32x4){0.f, 0.f, 0.f, 0.f};
    for (int k0 = 0; k0 < Kdim; k0 += 64) {
        for (int c = 0; c < 4; ++c) {
            int seg = c * 256 + tid;            // 0..1023
            int row = seg >> 3, ch = seg & 7;   // 8x16B chunks per 64-elem row
            const unsigned short* ga = A + (size_t)(m0 + row) * Kdim + k0 + ch * 8;
            const unsigned short* gb = Bt + (size_t)(n0 + row) * Kdim + k0 + ch * 8;
            int base = (c * 256 + wid * 64) * 8; // wave-uniform element base (linear)
            async16(ga, As + base);
            async16(gb, Bs + base);
        }
        __syncthreads();
        for (int kk = 0; kk < 64; kk += 32) {
            short8 af[4], bfr[4];
            for (int mi = 0; mi < 4; mi++)
                af[mi] = *(const short8*)(As + (wm * 64 + mi * 16 + l16) * 64 + kk + g * 8);
            for (int ni = 0; ni < 4; ni++)
                bfr[ni] = *(const short8*)(Bs + (wn * 64 + ni * 16 + l16) * 64 + kk + g * 8);
            for (int mi = 0; mi < 4; mi++)
                for (int ni = 0; ni < 4; ni++)
                    acc[mi][ni] = __builtin_amdgcn_mfma_f32_16x16x32_bf16(af[mi], bfr[ni], acc[mi][ni], 0, 0, 0);
        }
        __syncthreads();
    }
}

// ---------------- QKV projection GEMM, scatter epilogue ----------------
// Q output pre-scaled by 0.125*log2e (numerically free: bf16 rounding is relative).
__global__ __launch_bounds__(256) void k_gemm_qkv(
    const unsigned short* __restrict__ Xq, const unsigned short* __restrict__ Xk,
    const unsigned short* __restrict__ Xv,
    const unsigned short* __restrict__ Wtq, const unsigned short* __restrict__ Wtk,
    const unsigned short* __restrict__ Wtv,
    unsigned short* __restrict__ Qp, unsigned short* __restrict__ Kp,
    unsigned short* __restrict__ Vtp) {
    __shared__ unsigned short As[128 * 64], Bs[128 * 64];
    int z = blockIdx.z;
    const unsigned short* A = (z == 0) ? Xq : (z == 1) ? Xk : Xv;
    const unsigned short* Bt = (z == 0) ? Wtq : (z == 1) ? Wtk : Wtv;
    int m0 = blockIdx.y * 128, n0 = blockIdx.x * 128;
    f32x4 acc[4][4];
    gemm_tile64(A, Bt, CHN, m0, n0, acc, As, Bs);

    const int tid = threadIdx.x, lane = tid & 63, wid = tid >> 6;
    const int g = lane >> 4, l16 = lane & 15;
    const int wm = wid >> 1, wn = wid & 1;
    const float QSC = 0.125f * 1.4426950408889634f;
    if (z < 2) {
        unsigned short* dst = (z == 0) ? Qp : Kp;
        const float sc = (z == 0) ? QSC : 1.0f;
        for (int mi = 0; mi < 4; mi++)
            for (int ni = 0; ni < 4; ni++) {
                int col = n0 + wn * 64 + ni * 16 + l16;
                int h = col >> 6, d = col & 63;
                for (int r = 0; r < 4; r++) {
                    int m = m0 + wm * 64 + mi * 16 + g * 4 + r;
                    int b = m >> 10, i = m & 1023;
                    dst[(((size_t)b * NH + h) * SEQ + i) * DH + d] = f2bf(acc[mi][ni][r] * sc);
                }
            }
    } else {
        for (int mi = 0; mi < 4; mi++)
            for (int ni = 0; ni < 4; ni++) {
                int col = n0 + wn * 64 + ni * 16 + l16;
                int h = col >> 6, d = col & 63;
                int m = m0 + wm * 64 + mi * 16 + g * 4;
                int b = m >> 10, i = m & 1023;
                ushort4 pk;
                pk.x = f2bf(acc[mi][ni][0]); pk.y = f2bf(acc[mi][ni][1]);
                pk.z = f2bf(acc[mi][ni][2]); pk.w = f2bf(acc[mi][ni][3]);
                *(ushort4*)&Vtp[(((size_t)b * NH + h) * DH + d) * SEQ + i] = pk;
            }
    }
}

// ---------------- fused flash attention: 8 waves x 32 q-rows, double-buffered K/V ----------------
// Round-14 structure (best: 65us) + double-buffer: ONE barrier per tile instead
// of two, and the LDS-write of tile t+1 moves AFTER compute of tile t (issue
// global loads early, write late — T14). Safety: writes to buf[cur^1] race only
// with iter t-1's reads of buf[cur^1], which finished before this iter's barrier.
// Round-15 lesson: waves/CU is the resource, not blocks/CU — repartitioning at
// constant 16 waves/CU only added overhead (65->78us). Grid stays 512.
// Swapped QK^T (mfma(K,Q)): lane (g,l16) holds P[i=l16][j=jb*16+g*4+r] = exact
// B-operand layout of mfma_f32_16x16x16_bf16 -> PV from registers, no P LDS.
// K/V fragments read ONCE per wave-tile as transients, feed both m-fragments.
// Register budget: qf 16 + acc 32 + staging 8 + addr/transients ~25 ~= 70.
// launch_bounds(512,6) caps ~85 — margin. Tripwire: WRITE_SIZE (~17MB = clean).
__global__ __launch_bounds__(512, 6) void k_attn(const unsigned short* __restrict__ Qp,
                                                 const unsigned short* __restrict__ Kp,
                                                 const unsigned short* __restrict__ Vtp,
                                                 const float* __restrict__ bias_table,
                                                 unsigned short* __restrict__ AO) {
    __shared__ unsigned short K_lds[2][64 * 72];
    __shared__ unsigned short V_lds[2][64 * 72];
    __shared__ uint2 biasq[1276];  // biasq[t] = bf16{b[t..t+3]} * log2e
    const int bh = blockIdx.y;
    const int h = bh & (NH - 1);
    const int i0blk = blockIdx.x * 256;
    const int tid = threadIdx.x, lane = tid & 63, w = tid >> 6;  // w = 0..7
    const int g = lane >> 4, l16 = lane & 15;
    const unsigned short* Qb = Qp + (size_t)bh * SEQ * DH;
    const unsigned short* Kb = Kp + (size_t)bh * SEQ * DH;
    const unsigned short* Vb = Vtp + (size_t)bh * DH * SEQ;

    const float LOG2E = 1.4426950408889634f;
    for (int t = tid; t < 1276; t += 512) {
        const float* bp = bias_table + (size_t)(t + i0blk) * NH + h;
        unsigned int b0 = f2bf(bp[0 * NH] * LOG2E), b1 = f2bf(bp[1 * NH] * LOG2E);
        unsigned int b2 = f2bf(bp[2 * NH] * LOG2E), b3 = f2bf(bp[3 * NH] * LOG2E);
        uint2 q; q.x = (b1 << 16) | b0; q.y = (b3 << 16) | b2;
        biasq[t] = q;
    }

    const int iw = i0blk + w * 32;  // 32 q-rows per wave (2 m-fragments)
    short8 qf[2][2];
    for (int mf = 0; mf < 2; mf++)
        for (int f = 0; f < 2; f++)
            qf[mf][f] = *(const short8*)(Qb + (iw + mf * 16 + l16) * DH + f * 32 + g * 8);

    float lsum0 = 0.f, lsum1 = 0.f;
    f32x4 acc[2][4];  // acc[mf][db][r] = O[i=l16][d=db*16+g*4+r]
    for (int mf = 0; mf < 2; mf++)
        for (int db = 0; db < 4; db++) acc[mf][db] = (f32x4){0.f, 0.f, 0.f, 0.f};

    // staging: 512 threads, one 16B chunk each of K and V; prologue fills buf 0
    const int r0 = tid >> 3, c0 = tid & 7;  // rows 0..63, col-chunks 0..7
    const int soff = r0 * 72 + c0 * 8;
    int4 kr = *(const int4*)(Kb + (size_t)r0 * DH + c0 * 8);
    int4 vr = *(const int4*)(Vb + (size_t)r0 * SEQ + c0 * 8);
    *(int4*)(&K_lds[0][soff]) = kr;
    *(int4*)(&V_lds[0][soff]) = vr;

    int cur = 0;
    for (int j0 = 0; j0 < SEQ; j0 += 64, cur ^= 1) {
        __syncthreads();  // buf[cur] ready; everyone done reading buf[cur^1]

        const bool more = (j0 + 64 < SEQ);
        if (more) {  // issue next-tile loads NOW; vmcnt wait happens after compute
            const int jn = j0 + 64;
            kr = *(const int4*)(Kb + (size_t)(jn + r0) * DH + c0 * 8);
            vr = *(const int4*)(Vb + (size_t)r0 * SEQ + jn + c0 * 8);
        }

        const unsigned short* Kc = K_lds[cur];
        const unsigned short* Vc = V_lds[cur];
        const int bbB = (w * 32 + l16 + 1023) - j0 - g * 4;  // mf=0 base
        for (int jb = 0; jb < 4; jb++) {
            // K fragments read ONCE, feed both m-fragments
            short8 kf0 = *(const short8*)(&Kc[(jb * 16 + l16) * 72 + g * 8]);
            short8 kf1 = *(const short8*)(&Kc[(jb * 16 + l16) * 72 + 32 + g * 8]);
            const int bb0 = bbB - jb * 16;
            const uint2 bq0 = biasq[bb0 - 3];
            const uint2 bq1 = biasq[bb0 + 13];  // mf=1: bb + 16
            f32x4 s0 = {__uint_as_float(bq0.y & 0xffff0000u),
                        __uint_as_float(bq0.y << 16),
                        __uint_as_float(bq0.x & 0xffff0000u),
                        __uint_as_float(bq0.x << 16)};
            f32x4 s1 = {__uint_as_float(bq1.y & 0xffff0000u),
                        __uint_as_float(bq1.y << 16),
                        __uint_as_float(bq1.x & 0xffff0000u),
                        __uint_as_float(bq1.x << 16)};
            s0 = __builtin_amdgcn_mfma_f32_16x16x32_bf16(kf0, qf[0][0], s0, 0, 0, 0);
            s0 = __builtin_amdgcn_mfma_f32_16x16x32_bf16(kf1, qf[0][1], s0, 0, 0, 0);
            s1 = __builtin_amdgcn_mfma_f32_16x16x32_bf16(kf0, qf[1][0], s1, 0, 0, 0);
            s1 = __builtin_amdgcn_mfma_f32_16x16x32_bf16(kf1, qf[1][1], s1, 0, 0, 0);
            float p00 = __builtin_amdgcn_exp2f(s0[0]);
            float p01 = __builtin_amdgcn_exp2f(s0[1]);
            float p02 = __builtin_amdgcn_exp2f(s0[2]);
            float p03 = __builtin_amdgcn_exp2f(s0[3]);
            float p10 = __builtin_amdgcn_exp2f(s1[0]);
            float p11 = __builtin_amdgcn_exp2f(s1[1]);
            float p12 = __builtin_amdgcn_exp2f(s1[2]);
            float p13 = __builtin_amdgcn_exp2f(s1[3]);
            lsum0 += (p00 + p01) + (p02 + p03);
            lsum1 += (p10 + p11) + (p12 + p13);
            uint2 pd0, pd1;
            pd0.x = (unsigned int)f2bf(p00) | ((unsigned int)f2bf(p01) << 16);
            pd0.y = (unsigned int)f2bf(p02) | ((unsigned int)f2bf(p03) << 16);
            pd1.x = (unsigned int)f2bf(p10) | ((unsigned int)f2bf(p11) << 16);
            pd1.y = (unsigned int)f2bf(p12) | ((unsigned int)f2bf(p13) << 16);
            short4v pk0 = __builtin_bit_cast(short4v, pd0);
            short4v pk1 = __builtin_bit_cast(short4v, pd1);
            // V fragments read ONCE, feed both m-fragments' PV MFMAs
            for (int db = 0; db < 4; db++) {
                short4v vf = *(const short4v*)(&Vc[(db * 16 + l16) * 72 + jb * 16 + g * 4]);
                acc[0][db] = __builtin_amdgcn_mfma_f32_16x16x16bf16_1k(vf, pk0, acc[0][db], 0, 0, 0);
                acc[1][db] = __builtin_amdgcn_mfma_f32_16x16x16bf16_1k(vf, pk1, acc[1][db], 0, 0, 0);
            }
        }

        if (more) {  // write-late into the other buffer (T14)
            *(int4*)(&K_lds[cur ^ 1][soff]) = kr;
            *(int4*)(&V_lds[cur ^ 1][soff]) = vr;
        }
    }

    // row-sum: lanes l16, l16+16, l16+32, l16+48 hold disjoint j-slices of row i=l16
    float v0 = lsum0, v1 = lsum1;
    v0 += __shfl_xor(v0, 16, 64);
    v0 += __shfl_xor(v0, 32, 64);
    v1 += __shfl_xor(v1, 16, 64);
    v1 += __shfl_xor(v1, 32, 64);
    const float inv0 = 1.0f / v0;
    const float inv1 = 1.0f / v1;

    const int b = bh >> 3;
    for (int mf = 0; mf < 2; mf++) {
        const float inv = mf ? inv1 : inv0;
        const int i = iw + mf * 16 + l16;
        for (int db = 0; db < 4; db++) {
            ushort4 o;
            o.x = f2bf(acc[mf][db][0] * inv);
            o.y = f2bf(acc[mf][db][1] * inv);
            o.z = f2bf(acc[mf][db][2] * inv);
            o.w = f2bf(acc[mf][db][3] * inv);
            *(ushort4*)&AO[((size_t)b * SEQ + i) * CHN + h * DH + db * 16 + g * 4] = o;
        }
    }
}

// ---------------- output projection GEMM + bias, f32 out ----------------
__global__ __launch_bounds__(256) void k_gemm_out(const unsigned short* __restrict__ AOb,
                                                  const unsigned short* __restrict__ Wto,
                                                  const float* __restrict__ bo,
                                                  float* __restrict__ out) {
    __shared__ unsigned short As[128 * 64], Bs[128 * 64];
    int m0 = blockIdx.y * 128, n0 = blockIdx.x * 128;
    f32x4 acc[4][4];
    gemm_tile64(AOb, Wto, CHN, m0, n0, acc, As, Bs);
    const int tid = threadIdx.x, lane = tid & 63, wid = tid >> 6;
    const int g = lane >> 4, l16 = lane & 15;
    const int wm = wid >> 1, wn = wid & 1;
    for (int ni = 0; ni < 4; ni++) {
        int col = n0 + wn * 64 + ni * 16 + l16;
        float bias = bo[col];
        for (int mi = 0; mi < 4; mi++)
            for (int r = 0; r < 4; r++) {
                int m = m0 + wm * 64 + mi * 16 + g * 4 + r;
                out[(size_t)m * CHN + col] = acc[mi][ni][r] + bias;
            }
    }
}

extern "C" void kernel_launch(void* const* d_in, const int* in_sizes, int n_in,
                              void* d_out, int out_size, void* d_ws, size_t ws_size,
                              hipStream_t stream) {
    const float* q_f = (const float*)d_in[0];
    const float* k_f = (const float*)d_in[1];
    const float* v_f = (const float*)d_in[2];
    const float* Wq_f = (const float*)d_in[3];
    const float* Wk_f = (const float*)d_in[4];
    const float* Wv_f = (const float*)d_in[5];
    const float* Wo_f = (const float*)d_in[6];
    const float* bo_f = (const float*)d_in[7];
    const float* bt_f = (const float*)d_in[8];

    char* ws = (char*)d_ws;
    const size_t S_X = (size_t)BB * SEQ * CHN * 2;  // 16 MiB (bf16)
    const size_t S_W = (size_t)CHN * CHN * 2;       // 512 KiB

    unsigned short* Xq = (unsigned short*)(ws);
    unsigned short* Xk = (unsigned short*)(ws + S_X);
    unsigned short* Xv = (unsigned short*)(ws + 2 * S_X);
    unsigned short* Wtq = (unsigned short*)(ws + 3 * S_X);
    unsigned short* Wtk = (unsigned short*)(ws + 3 * S_X + S_W);
    unsigned short* Wtv = (unsigned short*)(ws + 3 * S_X + 2 * S_W);
    unsigned short* Wto = (unsigned short*)(ws + 3 * S_X + 3 * S_W);
    unsigned short* Qp = (unsigned short*)(ws + 3 * S_X + 4 * S_W);
    unsigned short* Kp = (unsigned short*)(ws + 4 * S_X + 4 * S_W);
    unsigned short* Vtp = (unsigned short*)(ws + 5 * S_X + 4 * S_W);
    unsigned short* AO = Xq;  // reuse: Xq dead after QKV GEMM

    const int n4 = BB * SEQ * CHN / 4;
    k_cvt3<<<dim3(n4 / 256, 3), 256, 0, stream>>>(q_f, k_f, v_f, Xq, Xk, Xv, n4);
    k_cvtw4<<<dim3(16, 16, 4), 256, 0, stream>>>(Wq_f, Wk_f, Wv_f, Wo_f, Wtq, Wtk, Wtv, Wto);

    k_gemm_qkv<<<dim3(CHN / 128, BB * SEQ / 128, 3), 256, 0, stream>>>(
        Xq, Xk, Xv, Wtq, Wtk, Wtv, Qp, Kp, Vtp);

    k_attn<<<dim3(SEQ / 256, BB * NH), 512, 0, stream>>>(Qp, Kp, Vtp, bt_f, AO);

    k_gemm_out<<<dim3(CHN / 128, BB * SEQ / 128), 256, 0, stream>>>(
        AO, Wto, bo_f, (float*)d_out);
}

// Round 17
// 518.766 us; speedup vs baseline: 1.0172x; 1.0172x over previous
//
#include <hip/hip_runtime.h>
#include <hip/hip_bf16.h>
#include <stdint.h>

#define BB 16
#define SEQ 1024
#define CHN 512
#define NH 8
#define DH 64

typedef short short8 __attribute__((ext_vector_type(8)));
typedef short short4v __attribute__((ext_vector_type(4)));
typedef float f32x4 __attribute__((ext_vector_type(4)));

typedef const __attribute__((address_space(1))) unsigned int* gptr_t;
typedef __attribute__((address_space(3))) unsigned int* lptr_t;

__device__ __forceinline__ void async16(const void* g, void* l) {
    __builtin_amdgcn_global_load_lds((gptr_t)g, (lptr_t)l, 16, 0, 0);
}

__device__ __forceinline__ unsigned short f2bf(float f) {
    unsigned int u = __float_as_uint(f);
    u += 0x7FFF + ((u >> 16) & 1);
    return (unsigned short)(u >> 16);
}

// ---------------- convert f32 -> bf16 (3 tensors, one launch) ----------------
// At HBM roofline (144 MB @ ~6 TB/s ~= 24 us) — do not fuse into the GEMM
// (round-10 regression: f32 A re-read 4x + sync reg-staging -> qkv 38->98us).
__global__ __launch_bounds__(256) void k_cvt3(const float* __restrict__ a, const float* __restrict__ b,
                                              const float* __restrict__ c,
                                              unsigned short* __restrict__ oa, unsigned short* __restrict__ ob,
                                              unsigned short* __restrict__ oc, int n4) {
    int i = blockIdx.x * 256 + threadIdx.x;
    if (i >= n4) return;
    const float* in = (blockIdx.y == 0) ? a : (blockIdx.y == 1) ? b : c;
    unsigned short* out = (blockIdx.y == 0) ? oa : (blockIdx.y == 1) ? ob : oc;
    float4 v = ((const float4*)in)[i];
    ushort4 o;
    o.x = f2bf(v.x); o.y = f2bf(v.y); o.z = f2bf(v.z); o.w = f2bf(v.w);
    ((ushort4*)out)[i] = o;
}

// ------- convert + transpose weights: W[k][n] -> Wt[n][k] bf16 (4 weights, one launch) -------
__global__ __launch_bounds__(256) void k_cvtw4(const float* __restrict__ W0, const float* __restrict__ W1,
                                               const float* __restrict__ W2, const float* __restrict__ W3,
                                               unsigned short* __restrict__ T0, unsigned short* __restrict__ T1,
                                               unsigned short* __restrict__ T2, unsigned short* __restrict__ T3) {
    __shared__ float t[32][33];
    int z = blockIdx.z;
    const float* W = (z == 0) ? W0 : (z == 1) ? W1 : (z == 2) ? W2 : W3;
    unsigned short* Wt = (z == 0) ? T0 : (z == 1) ? T1 : (z == 2) ? T2 : T3;
    int n0 = blockIdx.x * 32, k0 = blockIdx.y * 32;
    int tx = threadIdx.x & 31, ty = threadIdx.x >> 5;
    for (int r = ty; r < 32; r += 8) t[r][tx] = W[(k0 + r) * CHN + n0 + tx];
    __syncthreads();
    for (int r = ty; r < 32; r += 8) Wt[(n0 + r) * CHN + k0 + tx] = f2bf(t[tx][r]);
}

// ---------- shared GEMM core, BK=64: A[M,K] x Bt[N,K] (both bf16 row-major) ----------
__device__ __forceinline__ void gemm_tile64(const unsigned short* __restrict__ A,
                                            const unsigned short* __restrict__ Bt,
                                            int Kdim, int m0, int n0,
                                            f32x4 acc[4][4],
                                            unsigned short* As, unsigned short* Bs) {
    const int tid = threadIdx.x;
    const int lane = tid & 63, wid = tid >> 6;
    const int g = lane >> 4, l16 = lane & 15;
    const int wm = wid >> 1, wn = wid & 1;
    for (int i = 0; i < 4; i++)
        for (int j = 0; j < 4; j++) acc[i][j] = (f32x4){0.f, 0.f, 0.f, 0.f};
    for (int k0 = 0; k0 < Kdim; k0 += 64) {
        for (int c = 0; c < 4; ++c) {
            int seg = c * 256 + tid;            // 0..1023
            int row = seg >> 3, ch = seg & 7;   // 8x16B chunks per 64-elem row
            const unsigned short* ga = A + (size_t)(m0 + row) * Kdim + k0 + ch * 8;
            const unsigned short* gb = Bt + (size_t)(n0 + row) * Kdim + k0 + ch * 8;
            int base = (c * 256 + wid * 64) * 8; // wave-uniform element base (linear)
            async16(ga, As + base);
            async16(gb, Bs + base);
        }
        __syncthreads();
        for (int kk = 0; kk < 64; kk += 32) {
            short8 af[4], bfr[4];
            for (int mi = 0; mi < 4; mi++)
                af[mi] = *(const short8*)(As + (wm * 64 + mi * 16 + l16) * 64 + kk + g * 8);
            for (int ni = 0; ni < 4; ni++)
                bfr[ni] = *(const short8*)(Bs + (wn * 64 + ni * 16 + l16) * 64 + kk + g * 8);
            for (int mi = 0; mi < 4; mi++)
                for (int ni = 0; ni < 4; ni++)
                    acc[mi][ni] = __builtin_amdgcn_mfma_f32_16x16x32_bf16(af[mi], bfr[ni], acc[mi][ni], 0, 0, 0);
        }
        __syncthreads();
    }
}

// ---------------- QKV projection GEMM, scatter epilogue ----------------
// Q output pre-scaled by 0.125*log2e (numerically free: bf16 rounding is relative).
__global__ __launch_bounds__(256) void k_gemm_qkv(
    const unsigned short* __restrict__ Xq, const unsigned short* __restrict__ Xk,
    const unsigned short* __restrict__ Xv,
    const unsigned short* __restrict__ Wtq, const unsigned short* __restrict__ Wtk,
    const unsigned short* __restrict__ Wtv,
    unsigned short* __restrict__ Qp, unsigned short* __restrict__ Kp,
    unsigned short* __restrict__ Vtp) {
    __shared__ unsigned short As[128 * 64], Bs[128 * 64];
    int z = blockIdx.z;
    const unsigned short* A = (z == 0) ? Xq : (z == 1) ? Xk : Xv;
    const unsigned short* Bt = (z == 0) ? Wtq : (z == 1) ? Wtk : Wtv;
    int m0 = blockIdx.y * 128, n0 = blockIdx.x * 128;
    f32x4 acc[4][4];
    gemm_tile64(A, Bt, CHN, m0, n0, acc, As, Bs);

    const int tid = threadIdx.x, lane = tid & 63, wid = tid >> 6;
    const int g = lane >> 4, l16 = lane & 15;
    const int wm = wid >> 1, wn = wid & 1;
    const float QSC = 0.125f * 1.4426950408889634f;
    if (z < 2) {
        unsigned short* dst = (z == 0) ? Qp : Kp;
        const float sc = (z == 0) ? QSC : 1.0f;
        for (int mi = 0; mi < 4; mi++)
            for (int ni = 0; ni < 4; ni++) {
                int col = n0 + wn * 64 + ni * 16 + l16;
                int h = col >> 6, d = col & 63;
                for (int r = 0; r < 4; r++) {
                    int m = m0 + wm * 64 + mi * 16 + g * 4 + r;
                    int b = m >> 10, i = m & 1023;
                    dst[(((size_t)b * NH + h) * SEQ + i) * DH + d] = f2bf(acc[mi][ni][r] * sc);
                }
            }
    } else {
        for (int mi = 0; mi < 4; mi++)
            for (int ni = 0; ni < 4; ni++) {
                int col = n0 + wn * 64 + ni * 16 + l16;
                int h = col >> 6, d = col & 63;
                int m = m0 + wm * 64 + mi * 16 + g * 4;
                int b = m >> 10, i = m & 1023;
                ushort4 pk;
                pk.x = f2bf(acc[mi][ni][0]); pk.y = f2bf(acc[mi][ni][1]);
                pk.z = f2bf(acc[mi][ni][2]); pk.w = f2bf(acc[mi][ni][3]);
                *(ushort4*)&Vtp[(((size_t)b * NH + h) * DH + d) * SEQ + i] = pk;
            }
    }
}

// ---------------- fused flash attention: 8 waves x 32 q-rows (round-14 structure) ----------------
// PROVEN 65us structure: single-buffer, two barriers/tile, reg-prefetch of next
// tile between them. Round-15 (repartition 4wave/4blk: -20%) and round-16
// (manual double-buffer: compiler demoted staging regs to scratch, 996MB
// write traffic, 6.7x slower) both REGRESSED — do not touch the loop shape.
// This round adds only s_setprio(1) around MFMA clusters (T5, hint-only;
// +4-7% on attn per m191 when waves have role diversity between barriers).
// Swapped QK^T (mfma(K,Q)): lane (g,l16) holds P[i=l16][j=jb*16+g*4+r] = exact
// B-operand layout of mfma_f32_16x16x16_bf16 -> PV from registers, no P LDS.
// K/V fragments read ONCE per wave-tile as transients, feed both m-fragments.
__global__ __launch_bounds__(512, 6) void k_attn(const unsigned short* __restrict__ Qp,
                                                 const unsigned short* __restrict__ Kp,
                                                 const unsigned short* __restrict__ Vtp,
                                                 const float* __restrict__ bias_table,
                                                 unsigned short* __restrict__ AO) {
    __shared__ unsigned short K_lds[64 * 72];
    __shared__ unsigned short V_lds[64 * 72];
    __shared__ uint2 biasq[1280];  // biasq[t] = bf16{b[t..t+3]} * log2e
    const int bh = blockIdx.y;
    const int h = bh & (NH - 1);
    const int i0blk = blockIdx.x * 256;
    const int tid = threadIdx.x, lane = tid & 63, w = tid >> 6;  // w = 0..7
    const int g = lane >> 4, l16 = lane & 15;
    const unsigned short* Qb = Qp + (size_t)bh * SEQ * DH;
    const unsigned short* Kb = Kp + (size_t)bh * SEQ * DH;
    const unsigned short* Vb = Vtp + (size_t)bh * DH * SEQ;

    const float LOG2E = 1.4426950408889634f;
    for (int t = tid; t < 1276; t += 512) {
        const float* bp = bias_table + (size_t)(t + i0blk) * NH + h;
        unsigned int b0 = f2bf(bp[0 * NH] * LOG2E), b1 = f2bf(bp[1 * NH] * LOG2E);
        unsigned int b2 = f2bf(bp[2 * NH] * LOG2E), b3 = f2bf(bp[3 * NH] * LOG2E);
        uint2 q; q.x = (b1 << 16) | b0; q.y = (b3 << 16) | b2;
        biasq[t] = q;
    }

    const int iw = i0blk + w * 32;  // 32 q-rows per wave (2 m-fragments)
    short8 qf[2][2];
    for (int mf = 0; mf < 2; mf++)
        for (int f = 0; f < 2; f++)
            qf[mf][f] = *(const short8*)(Qb + (iw + mf * 16 + l16) * DH + f * 32 + g * 8);

    float lsum0 = 0.f, lsum1 = 0.f;
    f32x4 acc[2][4];  // acc[mf][db][r] = O[i=l16][d=db*16+g*4+r]
    for (int mf = 0; mf < 2; mf++)
        for (int db = 0; db < 4; db++) acc[mf][db] = (f32x4){0.f, 0.f, 0.f, 0.f};

    // staging: 512 threads, one 16B chunk each of K and V
    const int r0 = tid >> 3, c0 = tid & 7;  // rows 0..63, col-chunks 0..7
    int4 kr = *(const int4*)(Kb + (size_t)r0 * DH + c0 * 8);
    int4 vr = *(const int4*)(Vb + (size_t)r0 * SEQ + c0 * 8);

    for (int j0 = 0; j0 < SEQ; j0 += 64) {
        *(int4*)(&K_lds[r0 * 72 + c0 * 8]) = kr;
        *(int4*)(&V_lds[r0 * 72 + c0 * 8]) = vr;
        __syncthreads();

        // prefetch next tile into regs; HBM latency hides under this tile's compute
        if (j0 + 64 < SEQ) {
            const int jn = j0 + 64;
            kr = *(const int4*)(Kb + (size_t)(jn + r0) * DH + c0 * 8);
            vr = *(const int4*)(Vb + (size_t)r0 * SEQ + jn + c0 * 8);
        }

        const int bbB = (w * 32 + l16 + 1023) - j0 - g * 4;  // mf=0 base
        for (int jb = 0; jb < 4; jb++) {
            // K fragments read ONCE, feed both m-fragments
            short8 kf0 = *(const short8*)(&K_lds[(jb * 16 + l16) * 72 + g * 8]);
            short8 kf1 = *(const short8*)(&K_lds[(jb * 16 + l16) * 72 + 32 + g * 8]);
            const int bb0 = bbB - jb * 16;
            const uint2 bq0 = biasq[bb0 - 3];
            const uint2 bq1 = biasq[bb0 + 13];  // mf=1: bb + 16
            f32x4 s0 = {__uint_as_float(bq0.y & 0xffff0000u),
                        __uint_as_float(bq0.y << 16),
                        __uint_as_float(bq0.x & 0xffff0000u),
                        __uint_as_float(bq0.x << 16)};
            f32x4 s1 = {__uint_as_float(bq1.y & 0xffff0000u),
                        __uint_as_float(bq1.y << 16),
                        __uint_as_float(bq1.x & 0xffff0000u),
                        __uint_as_float(bq1.x << 16)};
            __builtin_amdgcn_s_setprio(1);
            s0 = __builtin_amdgcn_mfma_f32_16x16x32_bf16(kf0, qf[0][0], s0, 0, 0, 0);
            s0 = __builtin_amdgcn_mfma_f32_16x16x32_bf16(kf1, qf[0][1], s0, 0, 0, 0);
            s1 = __builtin_amdgcn_mfma_f32_16x16x32_bf16(kf0, qf[1][0], s1, 0, 0, 0);
            s1 = __builtin_amdgcn_mfma_f32_16x16x32_bf16(kf1, qf[1][1], s1, 0, 0, 0);
            __builtin_amdgcn_s_setprio(0);
            float p00 = __builtin_amdgcn_exp2f(s0[0]);
            float p01 = __builtin_amdgcn_exp2f(s0[1]);
            float p02 = __builtin_amdgcn_exp2f(s0[2]);
            float p03 = __builtin_amdgcn_exp2f(s0[3]);
            float p10 = __builtin_amdgcn_exp2f(s1[0]);
            float p11 = __builtin_amdgcn_exp2f(s1[1]);
            float p12 = __builtin_amdgcn_exp2f(s1[2]);
            float p13 = __builtin_amdgcn_exp2f(s1[3]);
            lsum0 += (p00 + p01) + (p02 + p03);
            lsum1 += (p10 + p11) + (p12 + p13);
            uint2 pd0, pd1;
            pd0.x = (unsigned int)f2bf(p00) | ((unsigned int)f2bf(p01) << 16);
            pd0.y = (unsigned int)f2bf(p02) | ((unsigned int)f2bf(p03) << 16);
            pd1.x = (unsigned int)f2bf(p10) | ((unsigned int)f2bf(p11) << 16);
            pd1.y = (unsigned int)f2bf(p12) | ((unsigned int)f2bf(p13) << 16);
            short4v pk0 = __builtin_bit_cast(short4v, pd0);
            short4v pk1 = __builtin_bit_cast(short4v, pd1);
            // V fragments read ONCE, feed both m-fragments' PV MFMAs
            __builtin_amdgcn_s_setprio(1);
            for (int db = 0; db < 4; db++) {
                short4v vf = *(const short4v*)(&V_lds[(db * 16 + l16) * 72 + jb * 16 + g * 4]);
                acc[0][db] = __builtin_amdgcn_mfma_f32_16x16x16bf16_1k(vf, pk0, acc[0][db], 0, 0, 0);
                acc[1][db] = __builtin_amdgcn_mfma_f32_16x16x16bf16_1k(vf, pk1, acc[1][db], 0, 0, 0);
            }
            __builtin_amdgcn_s_setprio(0);
        }
        __syncthreads();
    }

    // row-sum: lanes l16, l16+16, l16+32, l16+48 hold disjoint j-slices of row i=l16
    float v0 = lsum0, v1 = lsum1;
    v0 += __shfl_xor(v0, 16, 64);
    v0 += __shfl_xor(v0, 32, 64);
    v1 += __shfl_xor(v1, 16, 64);
    v1 += __shfl_xor(v1, 32, 64);
    const float inv0 = 1.0f / v0;
    const float inv1 = 1.0f / v1;

    const int b = bh >> 3;
    for (int mf = 0; mf < 2; mf++) {
        const float inv = mf ? inv1 : inv0;
        const int i = iw + mf * 16 + l16;
        for (int db = 0; db < 4; db++) {
            ushort4 o;
            o.x = f2bf(acc[mf][db][0] * inv);
            o.y = f2bf(acc[mf][db][1] * inv);
            o.z = f2bf(acc[mf][db][2] * inv);
            o.w = f2bf(acc[mf][db][3] * inv);
            *(ushort4*)&AO[((size_t)b * SEQ + i) * CHN + h * DH + db * 16 + g * 4] = o;
        }
    }
}

// ---------------- output projection GEMM + bias, f32 out ----------------
__global__ __launch_bounds__(256) void k_gemm_out(const unsigned short* __restrict__ AOb,
                                                  const unsigned short* __restrict__ Wto,
                                                  const float* __restrict__ bo,
                                                  float* __restrict__ out) {
    __shared__ unsigned short As[128 * 64], Bs[128 * 64];
    int m0 = blockIdx.y * 128, n0 = blockIdx.x * 128;
    f32x4 acc[4][4];
    gemm_tile64(AOb, Wto, CHN, m0, n0, acc, As, Bs);
    const int tid = threadIdx.x, lane = tid & 63, wid = tid >> 6;
    const int g = lane >> 4, l16 = lane & 15;
    const int wm = wid >> 1, wn = wid & 1;
    for (int ni = 0; ni < 4; ni++) {
        int col = n0 + wn * 64 + ni * 16 + l16;
        float bias = bo[col];
        for (int mi = 0; mi < 4; mi++)
            for (int r = 0; r < 4; r++) {
                int m = m0 + wm * 64 + mi * 16 + g * 4 + r;
                out[(size_t)m * CHN + col] = acc[mi][ni][r] + bias;
            }
    }
}

extern "C" void kernel_launch(void* const* d_in, const int* in_sizes, int n_in,
                              void* d_out, int out_size, void* d_ws, size_t ws_size,
                              hipStream_t stream) {
    const float* q_f = (const float*)d_in[0];
    const float* k_f = (const float*)d_in[1];
    const float* v_f = (const float*)d_in[2];
    const float* Wq_f = (const float*)d_in[3];
    const float* Wk_f = (const float*)d_in[4];
    const float* Wv_f = (const float*)d_in[5];
    const float* Wo_f = (const float*)d_in[6];
    const float* bo_f = (const float*)d_in[7];
    const float* bt_f = (const float*)d_in[8];

    char* ws = (char*)d_ws;
    const size_t S_X = (size_t)BB * SEQ * CHN * 2;  // 16 MiB (bf16)
    const size_t S_W = (size_t)CHN * CHN * 2;       // 512 KiB

    unsigned short* Xq = (unsigned short*)(ws);
    unsigned short* Xk = (unsigned short*)(ws + S_X);
    unsigned short* Xv = (unsigned short*)(ws + 2 * S_X);
    unsigned short* Wtq = (unsigned short*)(ws + 3 * S_X);
    unsigned short* Wtk = (unsigned short*)(ws + 3 * S_X + S_W);
    unsigned short* Wtv = (unsigned short*)(ws + 3 * S_X + 2 * S_W);
    unsigned short* Wto = (unsigned short*)(ws + 3 * S_X + 3 * S_W);
    unsigned short* Qp = (unsigned short*)(ws + 3 * S_X + 4 * S_W);
    unsigned short* Kp = (unsigned short*)(ws + 4 * S_X + 4 * S_W);
    unsigned short* Vtp = (unsigned short*)(ws + 5 * S_X + 4 * S_W);
    unsigned short* AO = Xq;  // reuse: Xq dead after QKV GEMM

    const int n4 = BB * SEQ * CHN / 4;
    k_cvt3<<<dim3(n4 / 256, 3), 256, 0, stream>>>(q_f, k_f, v_f, Xq, Xk, Xv, n4);
    k_cvtw4<<<dim3(16, 16, 4), 256, 0, stream>>>(Wq_f, Wk_f, Wv_f, Wo_f, Wtq, Wtk, Wtv, Wto);

    k_gemm_qkv<<<dim3(CHN / 128, BB * SEQ / 128, 3), 256, 0, stream>>>(
        Xq, Xk, Xv, Wtq, Wtk, Wtv, Qp, Kp, Vtp);

    k_attn<<<dim3(SEQ / 256, BB * NH), 512, 0, stream>>>(Qp, Kp, Vtp, bt_f, AO);

    k_gemm_out<<<dim3(CHN / 128, BB * SEQ / 128), 256, 0, stream>>>(
        AO, Wto, bo_f, (float*)d_out);
}

// Round 18
// 156.859 us; speedup vs baseline: 3.3643x; 3.3072x over previous
//
#include <hip/hip_runtime.h>
#include <hip/hip_bf16.h>
#include <stdint.h>

#define BB 16
#define SEQ 1024
#define CHN 512
#define NH 8
#define DH 64

typedef short short8 __attribute__((ext_vector_type(8)));
typedef short short4v __attribute__((ext_vector_type(4)));
typedef float f32x4 __attribute__((ext_vector_type(4)));

typedef const __attribute__((address_space(1))) unsigned int* gptr_t;
typedef __attribute__((address_space(3))) unsigned int* lptr_t;

__device__ __forceinline__ void async16(const void* g, void* l) {
    __builtin_amdgcn_global_load_lds((gptr_t)g, (lptr_t)l, 16, 0, 0);
}

__device__ __forceinline__ unsigned short f2bf(float f) {
    unsigned int u = __float_as_uint(f);
    u += 0x7FFF + ((u >> 16) & 1);
    return (unsigned short)(u >> 16);
}

// ---------------- convert f32 -> bf16 (3 tensors, one launch) ----------------
// At HBM roofline (144 MB @ ~6 TB/s ~= 24 us) — do not fuse into the GEMM
// (round-10 regression: f32 A re-read 4x + sync reg-staging -> qkv 38->98us).
__global__ __launch_bounds__(256) void k_cvt3(const float* __restrict__ a, const float* __restrict__ b,
                                              const float* __restrict__ c,
                                              unsigned short* __restrict__ oa, unsigned short* __restrict__ ob,
                                              unsigned short* __restrict__ oc, int n4) {
    int i = blockIdx.x * 256 + threadIdx.x;
    if (i >= n4) return;
    const float* in = (blockIdx.y == 0) ? a : (blockIdx.y == 1) ? b : c;
    unsigned short* out = (blockIdx.y == 0) ? oa : (blockIdx.y == 1) ? ob : oc;
    float4 v = ((const float4*)in)[i];
    ushort4 o;
    o.x = f2bf(v.x); o.y = f2bf(v.y); o.z = f2bf(v.z); o.w = f2bf(v.w);
    ((ushort4*)out)[i] = o;
}

// ------- convert + transpose weights: W[k][n] -> Wt[n][k] bf16 (4 weights, one launch) -------
__global__ __launch_bounds__(256) void k_cvtw4(const float* __restrict__ W0, const float* __restrict__ W1,
                                               const float* __restrict__ W2, const float* __restrict__ W3,
                                               unsigned short* __restrict__ T0, unsigned short* __restrict__ T1,
                                               unsigned short* __restrict__ T2, unsigned short* __restrict__ T3) {
    __shared__ float t[32][33];
    int z = blockIdx.z;
    const float* W = (z == 0) ? W0 : (z == 1) ? W1 : (z == 2) ? W2 : W3;
    unsigned short* Wt = (z == 0) ? T0 : (z == 1) ? T1 : (z == 2) ? T2 : T3;
    int n0 = blockIdx.x * 32, k0 = blockIdx.y * 32;
    int tx = threadIdx.x & 31, ty = threadIdx.x >> 5;
    for (int r = ty; r < 32; r += 8) t[r][tx] = W[(k0 + r) * CHN + n0 + tx];
    __syncthreads();
    for (int r = ty; r < 32; r += 8) Wt[(n0 + r) * CHN + k0 + tx] = f2bf(t[tx][r]);
}

// ---------- shared GEMM core, BK=64: A[M,K] x Bt[N,K] (both bf16 row-major) ----------
__device__ __forceinline__ void gemm_tile64(const unsigned short* __restrict__ A,
                                            const unsigned short* __restrict__ Bt,
                                            int Kdim, int m0, int n0,
                                            f32x4 acc[4][4],
                                            unsigned short* As, unsigned short* Bs) {
    const int tid = threadIdx.x;
    const int lane = tid & 63, wid = tid >> 6;
    const int g = lane >> 4, l16 = lane & 15;
    const int wm = wid >> 1, wn = wid & 1;
    for (int i = 0; i < 4; i++)
        for (int j = 0; j < 4; j++) acc[i][j] = (f32x4){0.f, 0.f, 0.f, 0.f};
    for (int k0 = 0; k0 < Kdim; k0 += 64) {
        for (int c = 0; c < 4; ++c) {
            int seg = c * 256 + tid;            // 0..1023
            int row = seg >> 3, ch = seg & 7;   // 8x16B chunks per 64-elem row
            const unsigned short* ga = A + (size_t)(m0 + row) * Kdim + k0 + ch * 8;
            const unsigned short* gb = Bt + (size_t)(n0 + row) * Kdim + k0 + ch * 8;
            int base = (c * 256 + wid * 64) * 8; // wave-uniform element base (linear)
            async16(ga, As + base);
            async16(gb, Bs + base);
        }
        __syncthreads();
        for (int kk = 0; kk < 64; kk += 32) {
            short8 af[4], bfr[4];
            for (int mi = 0; mi < 4; mi++)
                af[mi] = *(const short8*)(As + (wm * 64 + mi * 16 + l16) * 64 + kk + g * 8);
            for (int ni = 0; ni < 4; ni++)
                bfr[ni] = *(const short8*)(Bs + (wn * 64 + ni * 16 + l16) * 64 + kk + g * 8);
            for (int mi = 0; mi < 4; mi++)
                for (int ni = 0; ni < 4; ni++)
                    acc[mi][ni] = __builtin_amdgcn_mfma_f32_16x16x32_bf16(af[mi], bfr[ni], acc[mi][ni], 0, 0, 0);
        }
        __syncthreads();
    }
}

// ---------------- QKV projection GEMM, scatter epilogue ----------------
// Q output pre-scaled by 0.125*log2e (numerically free: bf16 rounding is relative).
__global__ __launch_bounds__(256) void k_gemm_qkv(
    const unsigned short* __restrict__ Xq, const unsigned short* __restrict__ Xk,
    const unsigned short* __restrict__ Xv,
    const unsigned short* __restrict__ Wtq, const unsigned short* __restrict__ Wtk,
    const unsigned short* __restrict__ Wtv,
    unsigned short* __restrict__ Qp, unsigned short* __restrict__ Kp,
    unsigned short* __restrict__ Vtp) {
    __shared__ unsigned short As[128 * 64], Bs[128 * 64];
    int z = blockIdx.z;
    const unsigned short* A = (z == 0) ? Xq : (z == 1) ? Xk : Xv;
    const unsigned short* Bt = (z == 0) ? Wtq : (z == 1) ? Wtk : Wtv;
    int m0 = blockIdx.y * 128, n0 = blockIdx.x * 128;
    f32x4 acc[4][4];
    gemm_tile64(A, Bt, CHN, m0, n0, acc, As, Bs);

    const int tid = threadIdx.x, lane = tid & 63, wid = tid >> 6;
    const int g = lane >> 4, l16 = lane & 15;
    const int wm = wid >> 1, wn = wid & 1;
    const float QSC = 0.125f * 1.4426950408889634f;
    if (z < 2) {
        unsigned short* dst = (z == 0) ? Qp : Kp;
        const float sc = (z == 0) ? QSC : 1.0f;
        for (int mi = 0; mi < 4; mi++)
            for (int ni = 0; ni < 4; ni++) {
                int col = n0 + wn * 64 + ni * 16 + l16;
                int h = col >> 6, d = col & 63;
                for (int r = 0; r < 4; r++) {
                    int m = m0 + wm * 64 + mi * 16 + g * 4 + r;
                    int b = m >> 10, i = m & 1023;
                    dst[(((size_t)b * NH + h) * SEQ + i) * DH + d] = f2bf(acc[mi][ni][r] * sc);
                }
            }
    } else {
        for (int mi = 0; mi < 4; mi++)
            for (int ni = 0; ni < 4; ni++) {
                int col = n0 + wn * 64 + ni * 16 + l16;
                int h = col >> 6, d = col & 63;
                int m = m0 + wm * 64 + mi * 16 + g * 4;
                int b = m >> 10, i = m & 1023;
                ushort4 pk;
                pk.x = f2bf(acc[mi][ni][0]); pk.y = f2bf(acc[mi][ni][1]);
                pk.z = f2bf(acc[mi][ni][2]); pk.w = f2bf(acc[mi][ni][3]);
                *(ushort4*)&Vtp[(((size_t)b * NH + h) * DH + d) * SEQ + i] = pk;
            }
    }
}

// ---------------- fused flash attention: 8 waves x 32 q-rows (round-14 EXACT) ----------------
// VERIFIED 65us / VGPR 64 / WRITE 17MB configuration. CRITICAL: launch_bounds
// MUST be (512,4) — (512,6) makes the compiler target ~40 VGPR for this
// 2-m-fragment kernel (needs ~100) -> ~900MB scratch spill traffic and 6.5x
// slowdown (rounds 16 AND 17 both hit this; the round-16 "double-buffer"
// blame was partly misattributed). Diff launch_bounds against last-known-good
// on EVERY edit.
// Swapped QK^T (mfma(K,Q)): lane (g,l16) holds P[i=l16][j=jb*16+g*4+r] = exact
// B-operand layout of mfma_f32_16x16x16_bf16 -> PV from registers, no P LDS.
// K/V fragments read ONCE per wave-tile as transients, feed both m-fragments.
__global__ __launch_bounds__(512, 4) void k_attn(const unsigned short* __restrict__ Qp,
                                                 const unsigned short* __restrict__ Kp,
                                                 const unsigned short* __restrict__ Vtp,
                                                 const float* __restrict__ bias_table,
                                                 unsigned short* __restrict__ AO) {
    __shared__ unsigned short K_lds[64 * 72];
    __shared__ unsigned short V_lds[64 * 72];
    __shared__ uint2 biasq[1280];  // biasq[t] = bf16{b[t..t+3]} * log2e, window 1279
    const int bh = blockIdx.y;
    const int h = bh & (NH - 1);
    const int i0blk = blockIdx.x * 256;
    const int tid = threadIdx.x, lane = tid & 63, w = tid >> 6;  // w = 0..7
    const int g = lane >> 4, l16 = lane & 15;
    const unsigned short* Qb = Qp + (size_t)bh * SEQ * DH;
    const unsigned short* Kb = Kp + (size_t)bh * SEQ * DH;
    const unsigned short* Vb = Vtp + (size_t)bh * DH * SEQ;

    const float LOG2E = 1.4426950408889634f;
    for (int t = tid; t < 1276; t += 512) {
        const float* bp = bias_table + (size_t)(t + i0blk) * NH + h;
        unsigned int b0 = f2bf(bp[0 * NH] * LOG2E), b1 = f2bf(bp[1 * NH] * LOG2E);
        unsigned int b2 = f2bf(bp[2 * NH] * LOG2E), b3 = f2bf(bp[3 * NH] * LOG2E);
        uint2 q; q.x = (b1 << 16) | b0; q.y = (b3 << 16) | b2;
        biasq[t] = q;
    }

    const int iw = i0blk + w * 32;  // 32 q-rows per wave (2 m-fragments)
    short8 qf[2][2];
    for (int mf = 0; mf < 2; mf++)
        for (int f = 0; f < 2; f++)
            qf[mf][f] = *(const short8*)(Qb + (iw + mf * 16 + l16) * DH + f * 32 + g * 8);

    float lsum0 = 0.f, lsum1 = 0.f;
    f32x4 acc[2][4];  // acc[mf][db][r] = O[i=l16][d=db*16+g*4+r]
    for (int mf = 0; mf < 2; mf++)
        for (int db = 0; db < 4; db++) acc[mf][db] = (f32x4){0.f, 0.f, 0.f, 0.f};

    // staging: 512 threads, one 16B chunk each of K and V
    const int r0 = tid >> 3, c0 = tid & 7;  // rows 0..63, col-chunks 0..7
    int4 kr = *(const int4*)(Kb + (size_t)r0 * DH + c0 * 8);
    int4 vr = *(const int4*)(Vb + (size_t)r0 * SEQ + c0 * 8);

    for (int j0 = 0; j0 < SEQ; j0 += 64) {
        *(int4*)(&K_lds[r0 * 72 + c0 * 8]) = kr;
        *(int4*)(&V_lds[r0 * 72 + c0 * 8]) = vr;
        __syncthreads();

        // prefetch next tile into regs; HBM latency hides under this tile's compute
        if (j0 + 64 < SEQ) {
            const int jn = j0 + 64;
            kr = *(const int4*)(Kb + (size_t)(jn + r0) * DH + c0 * 8);
            vr = *(const int4*)(Vb + (size_t)r0 * SEQ + jn + c0 * 8);
        }

        const int bbB = (w * 32 + l16 + 1023) - j0 - g * 4;  // mf=0 base
        for (int jb = 0; jb < 4; jb++) {
            // K fragments read ONCE, feed both m-fragments
            short8 kf0 = *(const short8*)(&K_lds[(jb * 16 + l16) * 72 + g * 8]);
            short8 kf1 = *(const short8*)(&K_lds[(jb * 16 + l16) * 72 + 32 + g * 8]);
            const int bb0 = bbB - jb * 16;
            const uint2 bq0 = biasq[bb0 - 3];
            const uint2 bq1 = biasq[bb0 + 13];  // mf=1: bb + 16
            f32x4 s0 = {__uint_as_float(bq0.y & 0xffff0000u),
                        __uint_as_float(bq0.y << 16),
                        __uint_as_float(bq0.x & 0xffff0000u),
                        __uint_as_float(bq0.x << 16)};
            f32x4 s1 = {__uint_as_float(bq1.y & 0xffff0000u),
                        __uint_as_float(bq1.y << 16),
                        __uint_as_float(bq1.x & 0xffff0000u),
                        __uint_as_float(bq1.x << 16)};
            s0 = __builtin_amdgcn_mfma_f32_16x16x32_bf16(kf0, qf[0][0], s0, 0, 0, 0);
            s0 = __builtin_amdgcn_mfma_f32_16x16x32_bf16(kf1, qf[0][1], s0, 0, 0, 0);
            s1 = __builtin_amdgcn_mfma_f32_16x16x32_bf16(kf0, qf[1][0], s1, 0, 0, 0);
            s1 = __builtin_amdgcn_mfma_f32_16x16x32_bf16(kf1, qf[1][1], s1, 0, 0, 0);
            float p00 = __builtin_amdgcn_exp2f(s0[0]);
            float p01 = __builtin_amdgcn_exp2f(s0[1]);
            float p02 = __builtin_amdgcn_exp2f(s0[2]);
            float p03 = __builtin_amdgcn_exp2f(s0[3]);
            float p10 = __builtin_amdgcn_exp2f(s1[0]);
            float p11 = __builtin_amdgcn_exp2f(s1[1]);
            float p12 = __builtin_amdgcn_exp2f(s1[2]);
            float p13 = __builtin_amdgcn_exp2f(s1[3]);
            lsum0 += (p00 + p01) + (p02 + p03);
            lsum1 += (p10 + p11) + (p12 + p13);
            uint2 pd0, pd1;
            pd0.x = (unsigned int)f2bf(p00) | ((unsigned int)f2bf(p01) << 16);
            pd0.y = (unsigned int)f2bf(p02) | ((unsigned int)f2bf(p03) << 16);
            pd1.x = (unsigned int)f2bf(p10) | ((unsigned int)f2bf(p11) << 16);
            pd1.y = (unsigned int)f2bf(p12) | ((unsigned int)f2bf(p13) << 16);
            short4v pk0 = __builtin_bit_cast(short4v, pd0);
            short4v pk1 = __builtin_bit_cast(short4v, pd1);
            // V fragments read ONCE, feed both m-fragments' PV MFMAs
            for (int db = 0; db < 4; db++) {
                short4v vf = *(const short4v*)(&V_lds[(db * 16 + l16) * 72 + jb * 16 + g * 4]);
                acc[0][db] = __builtin_amdgcn_mfma_f32_16x16x16bf16_1k(vf, pk0, acc[0][db], 0, 0, 0);
                acc[1][db] = __builtin_amdgcn_mfma_f32_16x16x16bf16_1k(vf, pk1, acc[1][db], 0, 0, 0);
            }
        }
        __syncthreads();
    }

    // row-sum: lanes l16, l16+16, l16+32, l16+48 hold disjoint j-slices of row i=l16
    float v0 = lsum0, v1 = lsum1;
    v0 += __shfl_xor(v0, 16, 64);
    v0 += __shfl_xor(v0, 32, 64);
    v1 += __shfl_xor(v1, 16, 64);
    v1 += __shfl_xor(v1, 32, 64);
    const float inv0 = 1.0f / v0;
    const float inv1 = 1.0f / v1;

    const int b = bh >> 3;
    for (int mf = 0; mf < 2; mf++) {
        const float inv = mf ? inv1 : inv0;
        const int i = iw + mf * 16 + l16;
        for (int db = 0; db < 4; db++) {
            ushort4 o;
            o.x = f2bf(acc[mf][db][0] * inv);
            o.y = f2bf(acc[mf][db][1] * inv);
            o.z = f2bf(acc[mf][db][2] * inv);
            o.w = f2bf(acc[mf][db][3] * inv);
            *(ushort4*)&AO[((size_t)b * SEQ + i) * CHN + h * DH + db * 16 + g * 4] = o;
        }
    }
}

// ---------------- output projection GEMM + bias, f32 out ----------------
__global__ __launch_bounds__(256) void k_gemm_out(const unsigned short* __restrict__ AOb,
                                                  const unsigned short* __restrict__ Wto,
                                                  const float* __restrict__ bo,
                                                  float* __restrict__ out) {
    __shared__ unsigned short As[128 * 64], Bs[128 * 64];
    int m0 = blockIdx.y * 128, n0 = blockIdx.x * 128;
    f32x4 acc[4][4];
    gemm_tile64(AOb, Wto, CHN, m0, n0, acc, As, Bs);
    const int tid = threadIdx.x, lane = tid & 63, wid = tid >> 6;
    const int g = lane >> 4, l16 = lane & 15;
    const int wm = wid >> 1, wn = wid & 1;
    for (int ni = 0; ni < 4; ni++) {
        int col = n0 + wn * 64 + ni * 16 + l16;
        float bias = bo[col];
        for (int mi = 0; mi < 4; mi++)
            for (int r = 0; r < 4; r++) {
                int m = m0 + wm * 64 + mi * 16 + g * 4 + r;
                out[(size_t)m * CHN + col] = acc[mi][ni][r] + bias;
            }
    }
}

extern "C" void kernel_launch(void* const* d_in, const int* in_sizes, int n_in,
                              void* d_out, int out_size, void* d_ws, size_t ws_size,
                              hipStream_t stream) {
    const float* q_f = (const float*)d_in[0];
    const float* k_f = (const float*)d_in[1];
    const float* v_f = (const float*)d_in[2];
    const float* Wq_f = (const float*)d_in[3];
    const float* Wk_f = (const float*)d_in[4];
    const float* Wv_f = (const float*)d_in[5];
    const float* Wo_f = (const float*)d_in[6];
    const float* bo_f = (const float*)d_in[7];
    const float* bt_f = (const float*)d_in[8];

    char* ws = (char*)d_ws;
    const size_t S_X = (size_t)BB * SEQ * CHN * 2;  // 16 MiB (bf16)
    const size_t S_W = (size_t)CHN * CHN * 2;       // 512 KiB

    unsigned short* Xq = (unsigned short*)(ws);
    unsigned short* Xk = (unsigned short*)(ws + S_X);
    unsigned short* Xv = (unsigned short*)(ws + 2 * S_X);
    unsigned short* Wtq = (unsigned short*)(ws + 3 * S_X);
    unsigned short* Wtk = (unsigned short*)(ws + 3 * S_X + S_W);
    unsigned short* Wtv = (unsigned short*)(ws + 3 * S_X + 2 * S_W);
    unsigned short* Wto = (unsigned short*)(ws + 3 * S_X + 3 * S_W);
    unsigned short* Qp = (unsigned short*)(ws + 3 * S_X + 4 * S_W);
    unsigned short* Kp = (unsigned short*)(ws + 4 * S_X + 4 * S_W);
    unsigned short* Vtp = (unsigned short*)(ws + 5 * S_X + 4 * S_W);
    unsigned short* AO = Xq;  // reuse: Xq dead after QKV GEMM

    const int n4 = BB * SEQ * CHN / 4;
    k_cvt3<<<dim3(n4 / 256, 3), 256, 0, stream>>>(q_f, k_f, v_f, Xq, Xk, Xv, n4);
    k_cvtw4<<<dim3(16, 16, 4), 256, 0, stream>>>(Wq_f, Wk_f, Wv_f, Wo_f, Wtq, Wtk, Wtv, Wto);

    k_gemm_qkv<<<dim3(CHN / 128, BB * SEQ / 128, 3), 256, 0, stream>>>(
        Xq, Xk, Xv, Wtq, Wtk, Wtv, Qp, Kp, Vtp);

    k_attn<<<dim3(SEQ / 256, BB * NH), 512, 0, stream>>>(Qp, Kp, Vtp, bt_f, AO);

    k_gemm_out<<<dim3(CHN / 128, BB * SEQ / 128), 256, 0, stream>>>(
        AO, Wto, bo_f, (float*)d_out);
}

// Round 19
// 154.563 us; speedup vs baseline: 3.4142x; 1.0149x over previous
//
#include <hip/hip_runtime.h>
#include <hip/hip_bf16.h>
#include <stdint.h>

#define BB 16
#define SEQ 1024
#define CHN 512
#define NH 8
#define DH 64

typedef short short8 __attribute__((ext_vector_type(8)));
typedef short short4v __attribute__((ext_vector_type(4)));
typedef float f32x4 __attribute__((ext_vector_type(4)));

typedef const __attribute__((address_space(1))) unsigned int* gptr_t;
typedef __attribute__((address_space(3))) unsigned int* lptr_t;

__device__ __forceinline__ void async16(const void* g, void* l) {
    __builtin_amdgcn_global_load_lds((gptr_t)g, (lptr_t)l, 16, 0, 0);
}

__device__ __forceinline__ unsigned short f2bf(float f) {
    unsigned int u = __float_as_uint(f);
    u += 0x7FFF + ((u >> 16) & 1);
    return (unsigned short)(u >> 16);
}

// ---------------- convert f32 -> bf16 (3 tensors, one launch) ----------------
// At HBM roofline (144 MB @ ~6 TB/s ~= 24 us) — do not fuse into the GEMM
// (round-10 regression: f32 A re-read 4x + sync reg-staging -> qkv 38->98us).
__global__ __launch_bounds__(256) void k_cvt3(const float* __restrict__ a, const float* __restrict__ b,
                                              const float* __restrict__ c,
                                              unsigned short* __restrict__ oa, unsigned short* __restrict__ ob,
                                              unsigned short* __restrict__ oc, int n4) {
    int i = blockIdx.x * 256 + threadIdx.x;
    if (i >= n4) return;
    const float* in = (blockIdx.y == 0) ? a : (blockIdx.y == 1) ? b : c;
    unsigned short* out = (blockIdx.y == 0) ? oa : (blockIdx.y == 1) ? ob : oc;
    float4 v = ((const float4*)in)[i];
    ushort4 o;
    o.x = f2bf(v.x); o.y = f2bf(v.y); o.z = f2bf(v.z); o.w = f2bf(v.w);
    ((ushort4*)out)[i] = o;
}

// ------- convert + transpose weights: W[k][n] -> Wt[n][k] bf16 (4 weights, one launch) -------
__global__ __launch_bounds__(256) void k_cvtw4(const float* __restrict__ W0, const float* __restrict__ W1,
                                               const float* __restrict__ W2, const float* __restrict__ W3,
                                               unsigned short* __restrict__ T0, unsigned short* __restrict__ T1,
                                               unsigned short* __restrict__ T2, unsigned short* __restrict__ T3) {
    __shared__ float t[32][33];
    int z = blockIdx.z;
    const float* W = (z == 0) ? W0 : (z == 1) ? W1 : (z == 2) ? W2 : W3;
    unsigned short* Wt = (z == 0) ? T0 : (z == 1) ? T1 : (z == 2) ? T2 : T3;
    int n0 = blockIdx.x * 32, k0 = blockIdx.y * 32;
    int tx = threadIdx.x & 31, ty = threadIdx.x >> 5;
    for (int r = ty; r < 32; r += 8) t[r][tx] = W[(k0 + r) * CHN + n0 + tx];
    __syncthreads();
    for (int r = ty; r < 32; r += 8) Wt[(n0 + r) * CHN + k0 + tx] = f2bf(t[tx][r]);
}

// ---- shared GEMM core, BK=64, 512 threads / 8 waves (2M x 4N): A[M,K] x Bt[N,K] ----
// Round-19: 8 waves/block doubles waves/CU (out: 4->8, qkv: 12->24) for barrier
// latency hiding. Each wave owns 64x32 output -> acc[4][2] = 32 VGPR (halved).
// async16 staging (no staging registers -> no spill surface). NO second
// launch_bounds arg — it was the root cause of all 3 spill catastrophes.
__device__ __forceinline__ void gemm_tile64_w8(const unsigned short* __restrict__ A,
                                               const unsigned short* __restrict__ Bt,
                                               int Kdim, int m0, int n0,
                                               f32x4 acc[4][2],
                                               unsigned short* As, unsigned short* Bs) {
    const int tid = threadIdx.x;
    const int lane = tid & 63, wid = tid >> 6;   // wid 0..7
    const int g = lane >> 4, l16 = lane & 15;
    const int wm = wid >> 2, wn = wid & 3;       // 2M x 4N wave grid
    for (int i = 0; i < 4; i++)
        for (int j = 0; j < 2; j++) acc[i][j] = (f32x4){0.f, 0.f, 0.f, 0.f};
    for (int k0 = 0; k0 < Kdim; k0 += 64) {
        for (int c = 0; c < 2; ++c) {
            int seg = c * 512 + tid;            // 0..1023
            int row = seg >> 3, ch = seg & 7;   // 8x16B chunks per 64-elem row
            const unsigned short* ga = A + (size_t)(m0 + row) * Kdim + k0 + ch * 8;
            const unsigned short* gb = Bt + (size_t)(n0 + row) * Kdim + k0 + ch * 8;
            int base = (c * 512 + wid * 64) * 8; // wave-uniform element base (linear)
            async16(ga, As + base);
            async16(gb, Bs + base);
        }
        __syncthreads();
        for (int kk = 0; kk < 64; kk += 32) {
            short8 af[4], bfr[2];
            for (int mi = 0; mi < 4; mi++)
                af[mi] = *(const short8*)(As + (wm * 64 + mi * 16 + l16) * 64 + kk + g * 8);
            for (int ni = 0; ni < 2; ni++)
                bfr[ni] = *(const short8*)(Bs + (wn * 32 + ni * 16 + l16) * 64 + kk + g * 8);
            for (int mi = 0; mi < 4; mi++)
                for (int ni = 0; ni < 2; ni++)
                    acc[mi][ni] = __builtin_amdgcn_mfma_f32_16x16x32_bf16(af[mi], bfr[ni], acc[mi][ni], 0, 0, 0);
        }
        __syncthreads();
    }
}

// ---------------- QKV projection GEMM, scatter epilogue ----------------
// Q output pre-scaled by 0.125*log2e (numerically free: bf16 rounding is relative).
__global__ __launch_bounds__(512) void k_gemm_qkv(
    const unsigned short* __restrict__ Xq, const unsigned short* __restrict__ Xk,
    const unsigned short* __restrict__ Xv,
    const unsigned short* __restrict__ Wtq, const unsigned short* __restrict__ Wtk,
    const unsigned short* __restrict__ Wtv,
    unsigned short* __restrict__ Qp, unsigned short* __restrict__ Kp,
    unsigned short* __restrict__ Vtp) {
    __shared__ unsigned short As[128 * 64], Bs[128 * 64];
    int z = blockIdx.z;
    const unsigned short* A = (z == 0) ? Xq : (z == 1) ? Xk : Xv;
    const unsigned short* Bt = (z == 0) ? Wtq : (z == 1) ? Wtk : Wtv;
    int m0 = blockIdx.y * 128, n0 = blockIdx.x * 128;
    f32x4 acc[4][2];
    gemm_tile64_w8(A, Bt, CHN, m0, n0, acc, As, Bs);

    const int tid = threadIdx.x, lane = tid & 63, wid = tid >> 6;
    const int g = lane >> 4, l16 = lane & 15;
    const int wm = wid >> 2, wn = wid & 3;
    const float QSC = 0.125f * 1.4426950408889634f;
    if (z < 2) {
        unsigned short* dst = (z == 0) ? Qp : Kp;
        const float sc = (z == 0) ? QSC : 1.0f;
        for (int mi = 0; mi < 4; mi++)
            for (int ni = 0; ni < 2; ni++) {
                int col = n0 + wn * 32 + ni * 16 + l16;
                int h = col >> 6, d = col & 63;
                for (int r = 0; r < 4; r++) {
                    int m = m0 + wm * 64 + mi * 16 + g * 4 + r;
                    int b = m >> 10, i = m & 1023;
                    dst[(((size_t)b * NH + h) * SEQ + i) * DH + d] = f2bf(acc[mi][ni][r] * sc);
                }
            }
    } else {
        for (int mi = 0; mi < 4; mi++)
            for (int ni = 0; ni < 2; ni++) {
                int col = n0 + wn * 32 + ni * 16 + l16;
                int h = col >> 6, d = col & 63;
                int m = m0 + wm * 64 + mi * 16 + g * 4;
                int b = m >> 10, i = m & 1023;
                ushort4 pk;
                pk.x = f2bf(acc[mi][ni][0]); pk.y = f2bf(acc[mi][ni][1]);
                pk.z = f2bf(acc[mi][ni][2]); pk.w = f2bf(acc[mi][ni][3]);
                *(ushort4*)&Vtp[(((size_t)b * NH + h) * DH + d) * SEQ + i] = pk;
            }
    }
}

// ---------------- fused flash attention: 8 waves x 32 q-rows (round-14 EXACT) ----------------
// VERIFIED 65us / VGPR 64 / WRITE 17MB configuration. CRITICAL: launch_bounds
// MUST be (512,4) — (512,6) makes the compiler target ~40 VGPR for this
// 2-m-fragment kernel (needs ~100) -> ~900MB scratch spill traffic and 6.5x
// slowdown (rounds 16 AND 17 both hit this). Diff launch_bounds against
// last-known-good on EVERY edit.
// Swapped QK^T (mfma(K,Q)): lane (g,l16) holds P[i=l16][j=jb*16+g*4+r] = exact
// B-operand layout of mfma_f32_16x16x16_bf16 -> PV from registers, no P LDS.
// K/V fragments read ONCE per wave-tile as transients, feed both m-fragments.
__global__ __launch_bounds__(512, 4) void k_attn(const unsigned short* __restrict__ Qp,
                                                 const unsigned short* __restrict__ Kp,
                                                 const unsigned short* __restrict__ Vtp,
                                                 const float* __restrict__ bias_table,
                                                 unsigned short* __restrict__ AO) {
    __shared__ unsigned short K_lds[64 * 72];
    __shared__ unsigned short V_lds[64 * 72];
    __shared__ uint2 biasq[1280];  // biasq[t] = bf16{b[t..t+3]} * log2e, window 1279
    const int bh = blockIdx.y;
    const int h = bh & (NH - 1);
    const int i0blk = blockIdx.x * 256;
    const int tid = threadIdx.x, lane = tid & 63, w = tid >> 6;  // w = 0..7
    const int g = lane >> 4, l16 = lane & 15;
    const unsigned short* Qb = Qp + (size_t)bh * SEQ * DH;
    const unsigned short* Kb = Kp + (size_t)bh * SEQ * DH;
    const unsigned short* Vb = Vtp + (size_t)bh * DH * SEQ;

    const float LOG2E = 1.4426950408889634f;
    for (int t = tid; t < 1276; t += 512) {
        const float* bp = bias_table + (size_t)(t + i0blk) * NH + h;
        unsigned int b0 = f2bf(bp[0 * NH] * LOG2E), b1 = f2bf(bp[1 * NH] * LOG2E);
        unsigned int b2 = f2bf(bp[2 * NH] * LOG2E), b3 = f2bf(bp[3 * NH] * LOG2E);
        uint2 q; q.x = (b1 << 16) | b0; q.y = (b3 << 16) | b2;
        biasq[t] = q;
    }

    const int iw = i0blk + w * 32;  // 32 q-rows per wave (2 m-fragments)
    short8 qf[2][2];
    for (int mf = 0; mf < 2; mf++)
        for (int f = 0; f < 2; f++)
            qf[mf][f] = *(const short8*)(Qb + (iw + mf * 16 + l16) * DH + f * 32 + g * 8);

    float lsum0 = 0.f, lsum1 = 0.f;
    f32x4 acc[2][4];  // acc[mf][db][r] = O[i=l16][d=db*16+g*4+r]
    for (int mf = 0; mf < 2; mf++)
        for (int db = 0; db < 4; db++) acc[mf][db] = (f32x4){0.f, 0.f, 0.f, 0.f};

    // staging: 512 threads, one 16B chunk each of K and V
    const int r0 = tid >> 3, c0 = tid & 7;  // rows 0..63, col-chunks 0..7
    int4 kr = *(const int4*)(Kb + (size_t)r0 * DH + c0 * 8);
    int4 vr = *(const int4*)(Vb + (size_t)r0 * SEQ + c0 * 8);

    for (int j0 = 0; j0 < SEQ; j0 += 64) {
        *(int4*)(&K_lds[r0 * 72 + c0 * 8]) = kr;
        *(int4*)(&V_lds[r0 * 72 + c0 * 8]) = vr;
        __syncthreads();

        // prefetch next tile into regs; HBM latency hides under this tile's compute
        if (j0 + 64 < SEQ) {
            const int jn = j0 + 64;
            kr = *(const int4*)(Kb + (size_t)(jn + r0) * DH + c0 * 8);
            vr = *(const int4*)(Vb + (size_t)r0 * SEQ + jn + c0 * 8);
        }

        const int bbB = (w * 32 + l16 + 1023) - j0 - g * 4;  // mf=0 base
        for (int jb = 0; jb < 4; jb++) {
            // K fragments read ONCE, feed both m-fragments
            short8 kf0 = *(const short8*)(&K_lds[(jb * 16 + l16) * 72 + g * 8]);
            short8 kf1 = *(const short8*)(&K_lds[(jb * 16 + l16) * 72 + 32 + g * 8]);
            const int bb0 = bbB - jb * 16;
            const uint2 bq0 = biasq[bb0 - 3];
            const uint2 bq1 = biasq[bb0 + 13];  // mf=1: bb + 16
            f32x4 s0 = {__uint_as_float(bq0.y & 0xffff0000u),
                        __uint_as_float(bq0.y << 16),
                        __uint_as_float(bq0.x & 0xffff0000u),
                        __uint_as_float(bq0.x << 16)};
            f32x4 s1 = {__uint_as_float(bq1.y & 0xffff0000u),
                        __uint_as_float(bq1.y << 16),
                        __uint_as_float(bq1.x & 0xffff0000u),
                        __uint_as_float(bq1.x << 16)};
            s0 = __builtin_amdgcn_mfma_f32_16x16x32_bf16(kf0, qf[0][0], s0, 0, 0, 0);
            s0 = __builtin_amdgcn_mfma_f32_16x16x32_bf16(kf1, qf[0][1], s0, 0, 0, 0);
            s1 = __builtin_amdgcn_mfma_f32_16x16x32_bf16(kf0, qf[1][0], s1, 0, 0, 0);
            s1 = __builtin_amdgcn_mfma_f32_16x16x32_bf16(kf1, qf[1][1], s1, 0, 0, 0);
            float p00 = __builtin_amdgcn_exp2f(s0[0]);
            float p01 = __builtin_amdgcn_exp2f(s0[1]);
            float p02 = __builtin_amdgcn_exp2f(s0[2]);
            float p03 = __builtin_amdgcn_exp2f(s0[3]);
            float p10 = __builtin_amdgcn_exp2f(s1[0]);
            float p11 = __builtin_amdgcn_exp2f(s1[1]);
            float p12 = __builtin_amdgcn_exp2f(s1[2]);
            float p13 = __builtin_amdgcn_exp2f(s1[3]);
            lsum0 += (p00 + p01) + (p02 + p03);
            lsum1 += (p10 + p11) + (p12 + p13);
            uint2 pd0, pd1;
            pd0.x = (unsigned int)f2bf(p00) | ((unsigned int)f2bf(p01) << 16);
            pd0.y = (unsigned int)f2bf(p02) | ((unsigned int)f2bf(p03) << 16);
            pd1.x = (unsigned int)f2bf(p10) | ((unsigned int)f2bf(p11) << 16);
            pd1.y = (unsigned int)f2bf(p12) | ((unsigned int)f2bf(p13) << 16);
            short4v pk0 = __builtin_bit_cast(short4v, pd0);
            short4v pk1 = __builtin_bit_cast(short4v, pd1);
            // V fragments read ONCE, feed both m-fragments' PV MFMAs
            for (int db = 0; db < 4; db++) {
                short4v vf = *(const short4v*)(&V_lds[(db * 16 + l16) * 72 + jb * 16 + g * 4]);
                acc[0][db] = __builtin_amdgcn_mfma_f32_16x16x16bf16_1k(vf, pk0, acc[0][db], 0, 0, 0);
                acc[1][db] = __builtin_amdgcn_mfma_f32_16x16x16bf16_1k(vf, pk1, acc[1][db], 0, 0, 0);
            }
        }
        __syncthreads();
    }

    // row-sum: lanes l16, l16+16, l16+32, l16+48 hold disjoint j-slices of row i=l16
    float v0 = lsum0, v1 = lsum1;
    v0 += __shfl_xor(v0, 16, 64);
    v0 += __shfl_xor(v0, 32, 64);
    v1 += __shfl_xor(v1, 16, 64);
    v1 += __shfl_xor(v1, 32, 64);
    const float inv0 = 1.0f / v0;
    const float inv1 = 1.0f / v1;

    const int b = bh >> 3;
    for (int mf = 0; mf < 2; mf++) {
        const float inv = mf ? inv1 : inv0;
        const int i = iw + mf * 16 + l16;
        for (int db = 0; db < 4; db++) {
            ushort4 o;
            o.x = f2bf(acc[mf][db][0] * inv);
            o.y = f2bf(acc[mf][db][1] * inv);
            o.z = f2bf(acc[mf][db][2] * inv);
            o.w = f2bf(acc[mf][db][3] * inv);
            *(ushort4*)&AO[((size_t)b * SEQ + i) * CHN + h * DH + db * 16 + g * 4] = o;
        }
    }
}

// ---------------- output projection GEMM + bias, f32 out ----------------
__global__ __launch_bounds__(512) void k_gemm_out(const unsigned short* __restrict__ AOb,
                                                  const unsigned short* __restrict__ Wto,
                                                  const float* __restrict__ bo,
                                                  float* __restrict__ out) {
    __shared__ unsigned short As[128 * 64], Bs[128 * 64];
    int m0 = blockIdx.y * 128, n0 = blockIdx.x * 128;
    f32x4 acc[4][2];
    gemm_tile64_w8(AOb, Wto, CHN, m0, n0, acc, As, Bs);
    const int tid = threadIdx.x, lane = tid & 63, wid = tid >> 6;
    const int g = lane >> 4, l16 = lane & 15;
    const int wm = wid >> 2, wn = wid & 3;
    for (int ni = 0; ni < 2; ni++) {
        int col = n0 + wn * 32 + ni * 16 + l16;
        float bias = bo[col];
        for (int mi = 0; mi < 4; mi++)
            for (int r = 0; r < 4; r++) {
                int m = m0 + wm * 64 + mi * 16 + g * 4 + r;
                out[(size_t)m * CHN + col] = acc[mi][ni][r] + bias;
            }
    }
}

extern "C" void kernel_launch(void* const* d_in, const int* in_sizes, int n_in,
                              void* d_out, int out_size, void* d_ws, size_t ws_size,
                              hipStream_t stream) {
    const float* q_f = (const float*)d_in[0];
    const float* k_f = (const float*)d_in[1];
    const float* v_f = (const float*)d_in[2];
    const float* Wq_f = (const float*)d_in[3];
    const float* Wk_f = (const float*)d_in[4];
    const float* Wv_f = (const float*)d_in[5];
    const float* Wo_f = (const float*)d_in[6];
    const float* bo_f = (const float*)d_in[7];
    const float* bt_f = (const float*)d_in[8];

    char* ws = (char*)d_ws;
    const size_t S_X = (size_t)BB * SEQ * CHN * 2;  // 16 MiB (bf16)
    const size_t S_W = (size_t)CHN * CHN * 2;       // 512 KiB

    unsigned short* Xq = (unsigned short*)(ws);
    unsigned short* Xk = (unsigned short*)(ws + S_X);
    unsigned short* Xv = (unsigned short*)(ws + 2 * S_X);
    unsigned short* Wtq = (unsigned short*)(ws + 3 * S_X);
    unsigned short* Wtk = (unsigned short*)(ws + 3 * S_X + S_W);
    unsigned short* Wtv = (unsigned short*)(ws + 3 * S_X + 2 * S_W);
    unsigned short* Wto = (unsigned short*)(ws + 3 * S_X + 3 * S_W);
    unsigned short* Qp = (unsigned short*)(ws + 3 * S_X + 4 * S_W);
    unsigned short* Kp = (unsigned short*)(ws + 4 * S_X + 4 * S_W);
    unsigned short* Vtp = (unsigned short*)(ws + 5 * S_X + 4 * S_W);
    unsigned short* AO = Xq;  // reuse: Xq dead after QKV GEMM

    const int n4 = BB * SEQ * CHN / 4;
    k_cvt3<<<dim3(n4 / 256, 3), 256, 0, stream>>>(q_f, k_f, v_f, Xq, Xk, Xv, n4);
    k_cvtw4<<<dim3(16, 16, 4), 256, 0, stream>>>(Wq_f, Wk_f, Wv_f, Wo_f, Wtq, Wtk, Wtv, Wto);

    k_gemm_qkv<<<dim3(CHN / 128, BB * SEQ / 128, 3), 512, 0, stream>>>(
        Xq, Xk, Xv, Wtq, Wtk, Wtv, Qp, Kp, Vtp);

    k_attn<<<dim3(SEQ / 256, BB * NH), 512, 0, stream>>>(Qp, Kp, Vtp, bt_f, AO);

    k_gemm_out<<<dim3(CHN / 128, BB * SEQ / 128), 512, 0, stream>>>(
        AO, Wto, bo_f, (float*)d_out);
}

// Round 20
// 153.342 us; speedup vs baseline: 3.4414x; 1.0080x over previous
//
#include <hip/hip_runtime.h>
#include <hip/hip_bf16.h>
#include <stdint.h>

#define BB 16
#define SEQ 1024
#define CHN 512
#define NH 8
#define DH 64

typedef short short8 __attribute__((ext_vector_type(8)));
typedef short short4v __attribute__((ext_vector_type(4)));
typedef float f32x4 __attribute__((ext_vector_type(4)));

typedef const __attribute__((address_space(1))) unsigned int* gptr_t;
typedef __attribute__((address_space(3))) unsigned int* lptr_t;

__device__ __forceinline__ void async16(const void* g, void* l) {
    __builtin_amdgcn_global_load_lds((gptr_t)g, (lptr_t)l, 16, 0, 0);
}

__device__ __forceinline__ unsigned short f2bf(float f) {
    unsigned int u = __float_as_uint(f);
    u += 0x7FFF + ((u >> 16) & 1);
    return (unsigned short)(u >> 16);
}

// ------ merged conversion: 3 tensors f32->bf16 + 4 weights f32->bf16 transposed ------
// Tensor path at HBM roofline (150 MB @ ~6.3 TB/s ~= 24 us); weight work (2.5 MB)
// rides along instead of a separate serial 4-us launch. Do NOT fuse conversion
// into the GEMM itself (round-10: f32 A re-read 4x + sync staging -> 2.6x slower).
__global__ __launch_bounds__(256) void k_cvt_all(
    const float* __restrict__ a, const float* __restrict__ b, const float* __restrict__ c,
    const float* __restrict__ W0, const float* __restrict__ W1,
    const float* __restrict__ W2, const float* __restrict__ W3,
    unsigned short* __restrict__ oa, unsigned short* __restrict__ ob,
    unsigned short* __restrict__ oc,
    unsigned short* __restrict__ T0, unsigned short* __restrict__ T1,
    unsigned short* __restrict__ T2, unsigned short* __restrict__ T3,
    int n4) {
    __shared__ float tt[32][33];
    const int x = blockIdx.x, y = blockIdx.y;
    if (x < 8192) {
        int i = x * 256 + threadIdx.x;
        if (i >= n4) return;
        const float* in = (y == 0) ? a : (y == 1) ? b : c;
        unsigned short* out = (y == 0) ? oa : (y == 1) ? ob : oc;
        float4 v = ((const float4*)in)[i];
        ushort4 o;
        o.x = f2bf(v.x); o.y = f2bf(v.y); o.z = f2bf(v.z); o.w = f2bf(v.w);
        ((ushort4*)out)[i] = o;
    } else {
        int t = y * 512 + (x - 8192);  // 1536 slots for 1024 weight tiles
        if (t >= 1024) return;
        int z = t >> 8, tile = t & 255;
        const float* W = (z == 0) ? W0 : (z == 1) ? W1 : (z == 2) ? W2 : W3;
        unsigned short* Wt = (z == 0) ? T0 : (z == 1) ? T1 : (z == 2) ? T2 : T3;
        int n0 = (tile & 15) * 32, k0 = (tile >> 4) * 32;
        int tx = threadIdx.x & 31, ty = threadIdx.x >> 5;
        for (int r = ty; r < 32; r += 8) tt[r][tx] = W[(k0 + r) * CHN + n0 + tx];
        __syncthreads();
        for (int r = ty; r < 32; r += 8) Wt[(n0 + r) * CHN + k0 + tx] = f2bf(tt[tx][r]);
    }
}

// ---- shared GEMM core, BK=64, 512 threads / 8 waves (2M x 4N): A[M,K] x Bt[N,K] ----
// async16 staging (no staging registers -> no spill surface). NO second
// launch_bounds arg — it was the root cause of all 3 spill catastrophes.
__device__ __forceinline__ void gemm_tile64_w8(const unsigned short* __restrict__ A,
                                               const unsigned short* __restrict__ Bt,
                                               int Kdim, int m0, int n0,
                                               f32x4 acc[4][2],
                                               unsigned short* As, unsigned short* Bs) {
    const int tid = threadIdx.x;
    const int lane = tid & 63, wid = tid >> 6;   // wid 0..7
    const int g = lane >> 4, l16 = lane & 15;
    const int wm = wid >> 2, wn = wid & 3;       // 2M x 4N wave grid
    for (int i = 0; i < 4; i++)
        for (int j = 0; j < 2; j++) acc[i][j] = (f32x4){0.f, 0.f, 0.f, 0.f};
    for (int k0 = 0; k0 < Kdim; k0 += 64) {
        for (int c = 0; c < 2; ++c) {
            int seg = c * 512 + tid;            // 0..1023
            int row = seg >> 3, ch = seg & 7;   // 8x16B chunks per 64-elem row
            const unsigned short* ga = A + (size_t)(m0 + row) * Kdim + k0 + ch * 8;
            const unsigned short* gb = Bt + (size_t)(n0 + row) * Kdim + k0 + ch * 8;
            int base = (c * 512 + wid * 64) * 8; // wave-uniform element base (linear)
            async16(ga, As + base);
            async16(gb, Bs + base);
        }
        __syncthreads();
        for (int kk = 0; kk < 64; kk += 32) {
            short8 af[4], bfr[2];
            for (int mi = 0; mi < 4; mi++)
                af[mi] = *(const short8*)(As + (wm * 64 + mi * 16 + l16) * 64 + kk + g * 8);
            for (int ni = 0; ni < 2; ni++)
                bfr[ni] = *(const short8*)(Bs + (wn * 32 + ni * 16 + l16) * 64 + kk + g * 8);
            for (int mi = 0; mi < 4; mi++)
                for (int ni = 0; ni < 2; ni++)
                    acc[mi][ni] = __builtin_amdgcn_mfma_f32_16x16x32_bf16(af[mi], bfr[ni], acc[mi][ni], 0, 0, 0);
        }
        __syncthreads();
    }
}

// ---------------- QKV projection GEMM, scatter epilogue ----------------
// Q output pre-scaled by 0.125*log2e (numerically free: bf16 rounding is relative).
__global__ __launch_bounds__(512) void k_gemm_qkv(
    const unsigned short* __restrict__ Xq, const unsigned short* __restrict__ Xk,
    const unsigned short* __restrict__ Xv,
    const unsigned short* __restrict__ Wtq, const unsigned short* __restrict__ Wtk,
    const unsigned short* __restrict__ Wtv,
    unsigned short* __restrict__ Qp, unsigned short* __restrict__ Kp,
    unsigned short* __restrict__ Vtp) {
    __shared__ unsigned short As[128 * 64], Bs[128 * 64];
    int z = blockIdx.z;
    const unsigned short* A = (z == 0) ? Xq : (z == 1) ? Xk : Xv;
    const unsigned short* Bt = (z == 0) ? Wtq : (z == 1) ? Wtk : Wtv;
    int m0 = blockIdx.y * 128, n0 = blockIdx.x * 128;
    f32x4 acc[4][2];
    gemm_tile64_w8(A, Bt, CHN, m0, n0, acc, As, Bs);

    const int tid = threadIdx.x, lane = tid & 63, wid = tid >> 6;
    const int g = lane >> 4, l16 = lane & 15;
    const int wm = wid >> 2, wn = wid & 3;
    const float QSC = 0.125f * 1.4426950408889634f;
    if (z < 2) {
        unsigned short* dst = (z == 0) ? Qp : Kp;
        const float sc = (z == 0) ? QSC : 1.0f;
        for (int mi = 0; mi < 4; mi++)
            for (int ni = 0; ni < 2; ni++) {
                int col = n0 + wn * 32 + ni * 16 + l16;
                int h = col >> 6, d = col & 63;
                for (int r = 0; r < 4; r++) {
                    int m = m0 + wm * 64 + mi * 16 + g * 4 + r;
                    int b = m >> 10, i = m & 1023;
                    dst[(((size_t)b * NH + h) * SEQ + i) * DH + d] = f2bf(acc[mi][ni][r] * sc);
                }
            }
    } else {
        for (int mi = 0; mi < 4; mi++)
            for (int ni = 0; ni < 2; ni++) {
                int col = n0 + wn * 32 + ni * 16 + l16;
                int h = col >> 6, d = col & 63;
                int m = m0 + wm * 64 + mi * 16 + g * 4;
                int b = m >> 10, i = m & 1023;
                ushort4 pk;
                pk.x = f2bf(acc[mi][ni][0]); pk.y = f2bf(acc[mi][ni][1]);
                pk.z = f2bf(acc[mi][ni][2]); pk.w = f2bf(acc[mi][ni][3]);
                *(ushort4*)&Vtp[(((size_t)b * NH + h) * DH + d) * SEQ + i] = pk;
            }
    }
}

// ---------------- fused flash attention: 8 waves x 32 q-rows (round-14 EXACT) ----------------
// VERIFIED 65us / VGPR 64 / WRITE 17MB configuration. CRITICAL: launch_bounds
// MUST be (512,4) — (512,6) makes the compiler target ~40 VGPR for this
// 2-m-fragment kernel (needs ~100) -> ~900MB scratch spill traffic and 6.5x
// slowdown (rounds 16 AND 17 both hit this). Diff launch_bounds against
// last-known-good on EVERY edit.
// Swapped QK^T (mfma(K,Q)): lane (g,l16) holds P[i=l16][j=jb*16+g*4+r] = exact
// B-operand layout of mfma_f32_16x16x16_bf16 -> PV from registers, no P LDS.
// K/V fragments read ONCE per wave-tile as transients, feed both m-fragments.
__global__ __launch_bounds__(512, 4) void k_attn(const unsigned short* __restrict__ Qp,
                                                 const unsigned short* __restrict__ Kp,
                                                 const unsigned short* __restrict__ Vtp,
                                                 const float* __restrict__ bias_table,
                                                 unsigned short* __restrict__ AO) {
    __shared__ unsigned short K_lds[64 * 72];
    __shared__ unsigned short V_lds[64 * 72];
    __shared__ uint2 biasq[1280];  // biasq[t] = bf16{b[t..t+3]} * log2e, window 1279
    const int bh = blockIdx.y;
    const int h = bh & (NH - 1);
    const int i0blk = blockIdx.x * 256;
    const int tid = threadIdx.x, lane = tid & 63, w = tid >> 6;  // w = 0..7
    const int g = lane >> 4, l16 = lane & 15;
    const unsigned short* Qb = Qp + (size_t)bh * SEQ * DH;
    const unsigned short* Kb = Kp + (size_t)bh * SEQ * DH;
    const unsigned short* Vb = Vtp + (size_t)bh * DH * SEQ;

    const float LOG2E = 1.4426950408889634f;
    for (int t = tid; t < 1276; t += 512) {
        const float* bp = bias_table + (size_t)(t + i0blk) * NH + h;
        unsigned int b0 = f2bf(bp[0 * NH] * LOG2E), b1 = f2bf(bp[1 * NH] * LOG2E);
        unsigned int b2 = f2bf(bp[2 * NH] * LOG2E), b3 = f2bf(bp[3 * NH] * LOG2E);
        uint2 q; q.x = (b1 << 16) | b0; q.y = (b3 << 16) | b2;
        biasq[t] = q;
    }

    const int iw = i0blk + w * 32;  // 32 q-rows per wave (2 m-fragments)
    short8 qf[2][2];
    for (int mf = 0; mf < 2; mf++)
        for (int f = 0; f < 2; f++)
            qf[mf][f] = *(const short8*)(Qb + (iw + mf * 16 + l16) * DH + f * 32 + g * 8);

    float lsum0 = 0.f, lsum1 = 0.f;
    f32x4 acc[2][4];  // acc[mf][db][r] = O[i=l16][d=db*16+g*4+r]
    for (int mf = 0; mf < 2; mf++)
        for (int db = 0; db < 4; db++) acc[mf][db] = (f32x4){0.f, 0.f, 0.f, 0.f};

    // staging: 512 threads, one 16B chunk each of K and V
    const int r0 = tid >> 3, c0 = tid & 7;  // rows 0..63, col-chunks 0..7
    int4 kr = *(const int4*)(Kb + (size_t)r0 * DH + c0 * 8);
    int4 vr = *(const int4*)(Vb + (size_t)r0 * SEQ + c0 * 8);

    for (int j0 = 0; j0 < SEQ; j0 += 64) {
        *(int4*)(&K_lds[r0 * 72 + c0 * 8]) = kr;
        *(int4*)(&V_lds[r0 * 72 + c0 * 8]) = vr;
        __syncthreads();

        // prefetch next tile into regs; HBM latency hides under this tile's compute
        if (j0 + 64 < SEQ) {
            const int jn = j0 + 64;
            kr = *(const int4*)(Kb + (size_t)(jn + r0) * DH + c0 * 8);
            vr = *(const int4*)(Vb + (size_t)r0 * SEQ + jn + c0 * 8);
        }

        const int bbB = (w * 32 + l16 + 1023) - j0 - g * 4;  // mf=0 base
        for (int jb = 0; jb < 4; jb++) {
            // K fragments read ONCE, feed both m-fragments
            short8 kf0 = *(const short8*)(&K_lds[(jb * 16 + l16) * 72 + g * 8]);
            short8 kf1 = *(const short8*)(&K_lds[(jb * 16 + l16) * 72 + 32 + g * 8]);
            const int bb0 = bbB - jb * 16;
            const uint2 bq0 = biasq[bb0 - 3];
            const uint2 bq1 = biasq[bb0 + 13];  // mf=1: bb + 16
            f32x4 s0 = {__uint_as_float(bq0.y & 0xffff0000u),
                        __uint_as_float(bq0.y << 16),
                        __uint_as_float(bq0.x & 0xffff0000u),
                        __uint_as_float(bq0.x << 16)};
            f32x4 s1 = {__uint_as_float(bq1.y & 0xffff0000u),
                        __uint_as_float(bq1.y << 16),
                        __uint_as_float(bq1.x & 0xffff0000u),
                        __uint_as_float(bq1.x << 16)};
            s0 = __builtin_amdgcn_mfma_f32_16x16x32_bf16(kf0, qf[0][0], s0, 0, 0, 0);
            s0 = __builtin_amdgcn_mfma_f32_16x16x32_bf16(kf1, qf[0][1], s0, 0, 0, 0);
            s1 = __builtin_amdgcn_mfma_f32_16x16x32_bf16(kf0, qf[1][0], s1, 0, 0, 0);
            s1 = __builtin_amdgcn_mfma_f32_16x16x32_bf16(kf1, qf[1][1], s1, 0, 0, 0);
            float p00 = __builtin_amdgcn_exp2f(s0[0]);
            float p01 = __builtin_amdgcn_exp2f(s0[1]);
            float p02 = __builtin_amdgcn_exp2f(s0[2]);
            float p03 = __builtin_amdgcn_exp2f(s0[3]);
            float p10 = __builtin_amdgcn_exp2f(s1[0]);
            float p11 = __builtin_amdgcn_exp2f(s1[1]);
            float p12 = __builtin_amdgcn_exp2f(s1[2]);
            float p13 = __builtin_amdgcn_exp2f(s1[3]);
            lsum0 += (p00 + p01) + (p02 + p03);
            lsum1 += (p10 + p11) + (p12 + p13);
            uint2 pd0, pd1;
            pd0.x = (unsigned int)f2bf(p00) | ((unsigned int)f2bf(p01) << 16);
            pd0.y = (unsigned int)f2bf(p02) | ((unsigned int)f2bf(p03) << 16);
            pd1.x = (unsigned int)f2bf(p10) | ((unsigned int)f2bf(p11) << 16);
            pd1.y = (unsigned int)f2bf(p12) | ((unsigned int)f2bf(p13) << 16);
            short4v pk0 = __builtin_bit_cast(short4v, pd0);
            short4v pk1 = __builtin_bit_cast(short4v, pd1);
            // V fragments read ONCE, feed both m-fragments' PV MFMAs
            for (int db = 0; db < 4; db++) {
                short4v vf = *(const short4v*)(&V_lds[(db * 16 + l16) * 72 + jb * 16 + g * 4]);
                acc[0][db] = __builtin_amdgcn_mfma_f32_16x16x16bf16_1k(vf, pk0, acc[0][db], 0, 0, 0);
                acc[1][db] = __builtin_amdgcn_mfma_f32_16x16x16bf16_1k(vf, pk1, acc[1][db], 0, 0, 0);
            }
        }
        __syncthreads();
    }

    // row-sum: lanes l16, l16+16, l16+32, l16+48 hold disjoint j-slices of row i=l16
    float v0 = lsum0, v1 = lsum1;
    v0 += __shfl_xor(v0, 16, 64);
    v0 += __shfl_xor(v0, 32, 64);
    v1 += __shfl_xor(v1, 16, 64);
    v1 += __shfl_xor(v1, 32, 64);
    const float inv0 = 1.0f / v0;
    const float inv1 = 1.0f / v1;

    const int b = bh >> 3;
    for (int mf = 0; mf < 2; mf++) {
        const float inv = mf ? inv1 : inv0;
        const int i = iw + mf * 16 + l16;
        for (int db = 0; db < 4; db++) {
            ushort4 o;
            o.x = f2bf(acc[mf][db][0] * inv);
            o.y = f2bf(acc[mf][db][1] * inv);
            o.z = f2bf(acc[mf][db][2] * inv);
            o.w = f2bf(acc[mf][db][3] * inv);
            *(ushort4*)&AO[((size_t)b * SEQ + i) * CHN + h * DH + db * 16 + g * 4] = o;
        }
    }
}

// ---------------- output projection GEMM + bias, f32 out ----------------
__global__ __launch_bounds__(512) void k_gemm_out(const unsigned short* __restrict__ AOb,
                                                  const unsigned short* __restrict__ Wto,
                                                  const float* __restrict__ bo,
                                                  float* __restrict__ out) {
    __shared__ unsigned short As[128 * 64], Bs[128 * 64];
    int m0 = blockIdx.y * 128, n0 = blockIdx.x * 128;
    f32x4 acc[4][2];
    gemm_tile64_w8(AOb, Wto, CHN, m0, n0, acc, As, Bs);
    const int tid = threadIdx.x, lane = tid & 63, wid = tid >> 6;
    const int g = lane >> 4, l16 = lane & 15;
    const int wm = wid >> 2, wn = wid & 3;
    for (int ni = 0; ni < 2; ni++) {
        int col = n0 + wn * 32 + ni * 16 + l16;
        float bias = bo[col];
        for (int mi = 0; mi < 4; mi++)
            for (int r = 0; r < 4; r++) {
                int m = m0 + wm * 64 + mi * 16 + g * 4 + r;
                out[(size_t)m * CHN + col] = acc[mi][ni][r] + bias;
            }
    }
}

extern "C" void kernel_launch(void* const* d_in, const int* in_sizes, int n_in,
                              void* d_out, int out_size, void* d_ws, size_t ws_size,
                              hipStream_t stream) {
    const float* q_f = (const float*)d_in[0];
    const float* k_f = (const float*)d_in[1];
    const float* v_f = (const float*)d_in[2];
    const float* Wq_f = (const float*)d_in[3];
    const float* Wk_f = (const float*)d_in[4];
    const float* Wv_f = (const float*)d_in[5];
    const float* Wo_f = (const float*)d_in[6];
    const float* bo_f = (const float*)d_in[7];
    const float* bt_f = (const float*)d_in[8];

    char* ws = (char*)d_ws;
    const size_t S_X = (size_t)BB * SEQ * CHN * 2;  // 16 MiB (bf16)
    const size_t S_W = (size_t)CHN * CHN * 2;       // 512 KiB

    unsigned short* Xq = (unsigned short*)(ws);
    unsigned short* Xk = (unsigned short*)(ws + S_X);
    unsigned short* Xv = (unsigned short*)(ws + 2 * S_X);
    unsigned short* Wtq = (unsigned short*)(ws + 3 * S_X);
    unsigned short* Wtk = (unsigned short*)(ws + 3 * S_X + S_W);
    unsigned short* Wtv = (unsigned short*)(ws + 3 * S_X + 2 * S_W);
    unsigned short* Wto = (unsigned short*)(ws + 3 * S_X + 3 * S_W);
    unsigned short* Qp = (unsigned short*)(ws + 3 * S_X + 4 * S_W);
    unsigned short* Kp = (unsigned short*)(ws + 4 * S_X + 4 * S_W);
    unsigned short* Vtp = (unsigned short*)(ws + 5 * S_X + 4 * S_W);
    unsigned short* AO = Xq;  // reuse: Xq dead after QKV GEMM

    const int n4 = BB * SEQ * CHN / 4;  // 2,097,152 = 8192 * 256
    k_cvt_all<<<dim3(8704, 3), 256, 0, stream>>>(
        q_f, k_f, v_f, Wq_f, Wk_f, Wv_f, Wo_f,
        Xq, Xk, Xv, Wtq, Wtk, Wtv, Wto, n4);

    k_gemm_qkv<<<dim3(CHN / 128, BB * SEQ / 128, 3), 512, 0, stream>>>(
        Xq, Xk, Xv, Wtq, Wtk, Wtv, Qp, Kp, Vtp);

    k_attn<<<dim3(SEQ / 256, BB * NH), 512, 0, stream>>>(Qp, Kp, Vtp, bt_f, AO);

    k_gemm_out<<<dim3(CHN / 128, BB * SEQ / 128), 512, 0, stream>>>(
        AO, Wto, bo_f, (float*)d_out);
}